// Round 1
// baseline (2023.358 us; speedup 1.0000x reference)
//
#include <hip/hip_runtime.h>

// ---------------------------------------------------------------------------
// Fused LeViT-attention block for MI355X (gfx950).
// Pipeline: LN -> QKV GEMM (bf16 MFMA) -> flash attn w/ bias -> proj GEMM.
// All matmuls in bf16 MFMA 16x16x32 (no fp32 MFMA on CDNA4).
// Workspace layout (needs >= 280 MiB):
//   [0,64Mi)    xn bf16 [16384][2048]  (reused as attn_out after GEMM1)
//   [64,88Mi)   qkv_wt bf16 [6144][2048]  (reused for proj_wt [2048][2048])
//   [88,152Mi)  q bf16 [b][h][n][d] (pre-scaled by 128^-0.5)
//   [152,216Mi) k bf16 [b][h][n][d]
//   [216,280Mi) vT bf16 [b][h][d][n]
// ---------------------------------------------------------------------------

typedef __attribute__((ext_vector_type(4))) float          f32x4;
typedef __attribute__((ext_vector_type(8))) short          bf16x8;
typedef __attribute__((ext_vector_type(8))) unsigned short u16x8;
typedef __attribute__((ext_vector_type(4))) unsigned short u16x4;

#define DEV __device__ __forceinline__

DEV unsigned short f2bf(float f) {
  union { float f; unsigned int u; } v; v.f = f;
  unsigned int r = v.u + 0x7fffu + ((v.u >> 16) & 1u);   // RNE
  return (unsigned short)(r >> 16);
}

DEV f32x4 mfma16(bf16x8 a, bf16x8 b, f32x4 c) {
  return __builtin_amdgcn_mfma_f32_16x16x32_bf16(a, b, c, 0, 0, 0);
}

#define GLD_LDS16(g, l) __builtin_amdgcn_global_load_lds(                      \
    (const __attribute__((address_space(1))) void*)(g),                        \
    (__attribute__((address_space(3))) void*)(l), 16, 0, 0)

// ---------------------------------------------------------------------------
// LayerNorm: one block per row (2048 elems), fp32 in -> bf16 out.
// ---------------------------------------------------------------------------
__global__ __launch_bounds__(256) void ln_kernel(
    const float* __restrict__ x, const float* __restrict__ gam,
    const float* __restrict__ bet, unsigned short* __restrict__ xn)
{
  const int row = blockIdx.x;
  const int t   = threadIdx.x;
  const f32x4* xr = (const f32x4*)(x + (size_t)row * 2048);
  f32x4 v0 = xr[t * 2], v1 = xr[t * 2 + 1];
  float s = 0.f, ss = 0.f;
#pragma unroll
  for (int i = 0; i < 4; ++i) { s += v0[i]; ss += v0[i] * v0[i]; }
#pragma unroll
  for (int i = 0; i < 4; ++i) { s += v1[i]; ss += v1[i] * v1[i]; }
#pragma unroll
  for (int off = 32; off; off >>= 1) {
    s  += __shfl_xor(s, off);
    ss += __shfl_xor(ss, off);
  }
  __shared__ float r0[4], r1[4];
  const int w = t >> 6, lane = t & 63;
  if (lane == 0) { r0[w] = s; r1[w] = ss; }
  __syncthreads();
  s  = r0[0] + r0[1] + r0[2] + r0[3];
  ss = r1[0] + r1[1] + r1[2] + r1[3];
  const float mu = s * (1.f / 2048.f);
  const float rs = rsqrtf(ss * (1.f / 2048.f) - mu * mu + 1e-5f);
  const f32x4* gr = (const f32x4*)gam;
  const f32x4* br = (const f32x4*)bet;
  f32x4 g0 = gr[t * 2], g1 = gr[t * 2 + 1];
  f32x4 b0 = br[t * 2], b1 = br[t * 2 + 1];
  u16x8 o;
#pragma unroll
  for (int i = 0; i < 4; ++i) o[i]     = f2bf((v0[i] - mu) * rs * g0[i] + b0[i]);
#pragma unroll
  for (int i = 0; i < 4; ++i) o[4 + i] = f2bf((v1[i] - mu) * rs * g1[i] + b1[i]);
  *(u16x8*)(xn + (size_t)row * 2048 + t * 8) = o;
}

// ---------------------------------------------------------------------------
// Weight transpose + fp32->bf16: W[K][C] -> Wt[C][K]. 32x32 LDS tiles.
// ---------------------------------------------------------------------------
__global__ __launch_bounds__(256) void wtrans(
    const float* __restrict__ W, unsigned short* __restrict__ Wt, int K, int C)
{
  __shared__ float tile[32][33];
  const int c0 = blockIdx.x * 32, k0 = blockIdx.y * 32;
  const int t = threadIdx.x;
  const int r8 = t >> 5, c32 = t & 31;
#pragma unroll
  for (int i = 0; i < 4; ++i)
    tile[i * 8 + r8][c32] = W[(size_t)(k0 + i * 8 + r8) * C + c0 + c32];
  __syncthreads();
#pragma unroll
  for (int i = 0; i < 4; ++i)
    Wt[(size_t)(c0 + i * 8 + r8) * K + k0 + c32] = f2bf(tile[c32][i * 8 + r8]);
}

// ---------------------------------------------------------------------------
// NT GEMM: C[m][c] = sum_k A[m][k]*Wt[c][k] + bias[c].
// 128x128 tile, BK=64, 4 waves (2x2), global_load_lds w/ pre-swizzled src,
// XOR-swizzled ds_read_b128 (conflict-free), 2-phase double buffer.
// EPI=0: scatter q(scaled)/k/vT.  EPI=1: fp32 out + bias.
// ---------------------------------------------------------------------------
template <int EPI>
__global__ __launch_bounds__(256, 2) void gemm_nt(
    const unsigned short* __restrict__ A, const unsigned short* __restrict__ Wt,
    const float* __restrict__ bias, void* __restrict__ o0,
    void* __restrict__ o1, void* __restrict__ o2, int K, int C)
{
  __shared__ unsigned short lds[2][2][8192];   // [buf][A/B][128 rows x 64 bf16]
  const int m0 = blockIdx.y * 128, n0 = blockIdx.x * 128;
  const int tid = threadIdx.x, lane = tid & 63, w = tid >> 6;
  const int lhi = lane >> 4, llo = lane & 15;
  const int wr = w >> 1, wc = w & 1;

  const unsigned short* Ab = A  + (size_t)m0 * K;
  const unsigned short* Bb = Wt + (size_t)n0 * K;

  f32x4 acc[4][4];
#pragma unroll
  for (int i = 0; i < 4; ++i)
#pragma unroll
    for (int j = 0; j < 4; ++j) { acc[i][j][0] = 0; acc[i][j][1] = 0; acc[i][j][2] = 0; acc[i][j][3] = 0; }

  auto stage = [&](int kt, int buf) {
    const int k0 = kt * 64;
#pragma unroll
    for (int i = 0; i < 4; ++i) {
      const int c    = w * 4 + i;             // 16B chunk id (16 per matrix)
      const int row  = c * 8 + (lane >> 3);   // tile row (128B rows)
      const int colb = (lane & 7) * 16;       // linear LDS byte col
      const int scol = (colb ^ ((row & 7) << 4)) >> 1;  // swizzled src elem
      GLD_LDS16(Ab + (size_t)row * K + k0 + scol, &lds[buf][0][c * 512]);
      GLD_LDS16(Bb + (size_t)row * K + k0 + scol, &lds[buf][1][c * 512]);
    }
  };

  stage(0, 0);
  __syncthreads();
  const int nk = K >> 6;
  int cur = 0;
  for (int kt = 0; kt < nk; ++kt) {
    if (kt + 1 < nk) stage(kt + 1, cur ^ 1);
    const char* aL = (const char*)&lds[cur][0][0];
    const char* bL = (const char*)&lds[cur][1][0];
#pragma unroll
    for (int kk = 0; kk < 2; ++kk) {
      const int kb = kk * 64 + lhi * 16;
      bf16x8 af[4], bf[4];
#pragma unroll
      for (int t2 = 0; t2 < 4; ++t2) {
        const int ra = wr * 64 + t2 * 16 + llo;
        af[t2] = *(const bf16x8*)(aL + ra * 128 + (kb ^ ((ra & 7) << 4)));
        const int rb = wc * 64 + t2 * 16 + llo;
        bf[t2] = *(const bf16x8*)(bL + rb * 128 + (kb ^ ((rb & 7) << 4)));
      }
#pragma unroll
      for (int ai = 0; ai < 4; ++ai)
#pragma unroll
        for (int bj = 0; bj < 4; ++bj)
          acc[ai][bj] = mfma16(af[ai], bf[bj], acc[ai][bj]);
    }
    __syncthreads();
    cur ^= 1;
  }

  if (EPI == 0) {
    // block-uniform: which (q/k/v) and head h  (BN=128 divides H*D=2048 tiles)
    unsigned short* q  = (unsigned short*)o0;
    unsigned short* kk = (unsigned short*)o1;
    unsigned short* vT = (unsigned short*)o2;
    const int which = n0 >> 11;
    const int h     = (n0 >> 7) & 15;
#pragma unroll
    for (int bj = 0; bj < 4; ++bj) {
      const int c  = n0 + wc * 64 + bj * 16 + llo;
      const float bv = bias[c];
      const int d  = c & 127;
#pragma unroll
      for (int ai = 0; ai < 4; ++ai) {
        const int m = m0 + wr * 64 + ai * 16 + lhi * 4;
        const int b = m >> 10, n = m & 1023;
        if (which == 2) {
          u16x4 pk;
#pragma unroll
          for (int r = 0; r < 4; ++r) pk[r] = f2bf(acc[ai][bj][r] + bv);
          *(u16x4*)(vT + ((size_t)(b * 16 + h) * 128 + d) * 1024 + n) = pk;
        } else {
          unsigned short* dst = (which == 0) ? q : kk;
          const float sc = (which == 0) ? 0.08838834764831845f : 1.0f;
#pragma unroll
          for (int r = 0; r < 4; ++r)
            dst[((size_t)(b * 16 + h) * 1024 + n + r) * 128 + d] =
                f2bf((acc[ai][bj][r] + bv) * sc);
        }
      }
    }
  } else {
    float* fo = (float*)o0;
#pragma unroll
    for (int bj = 0; bj < 4; ++bj) {
      const int c  = n0 + wc * 64 + bj * 16 + llo;
      const float bv = bias[c];
#pragma unroll
      for (int ai = 0; ai < 4; ++ai) {
        const int m = m0 + wr * 64 + ai * 16 + lhi * 4;
#pragma unroll
        for (int r = 0; r < 4; ++r)
          fo[(size_t)(m + r) * C + c] = acc[ai][bj][r] + bv;
      }
    }
  }
}

// ---------------------------------------------------------------------------
// Flash attention with relative-position bias.
// Grid: B*H*(N/64) blocks; 4 waves/block, each wave owns 16 q-rows.
// K/V fragments read direct from global (L2-resident per (b,h)).
// P transposed for PV via per-wave XOR-swizzled LDS.
// ---------------------------------------------------------------------------
__global__ __launch_bounds__(256, 2) void attn_kernel(
    const unsigned short* __restrict__ q, const unsigned short* __restrict__ k,
    const unsigned short* __restrict__ vT, const float* __restrict__ biases,
    const int* __restrict__ idxs, unsigned short* __restrict__ aout, int n_off)
{
  const int bid = blockIdx.x;
  const int qt = bid & 15, bh = bid >> 4;
  const int h = bh & 15, b = bh >> 4;
  const int tid = threadIdx.x;
  const int lane = tid & 63, w = tid >> 6;
  const int lhi = lane >> 4, llo = lane & 15;

  __shared__ float biasrow[1024];
  __shared__ unsigned short plds[4][1024];   // per-wave 16x64 bf16, swizzled

  for (int i = tid; i < n_off; i += 256) biasrow[i] = biases[h * n_off + i];
  __syncthreads();

  const size_t hd = (size_t)(b * 16 + h) * (1024 * 128);
  const unsigned short* qp = q  + hd;
  const unsigned short* kp = k  + hd;
  const unsigned short* vp = vT + hd;      // [128][1024]
  const int qrow0 = qt * 64 + w * 16;

  bf16x8 qf[4];
#pragma unroll
  for (int kk = 0; kk < 4; ++kk)
    qf[kk] = *(const bf16x8*)(qp + (size_t)(qrow0 + llo) * 128 + kk * 32 + lhi * 8);

  f32x4 o[8];
#pragma unroll
  for (int nd = 0; nd < 8; ++nd) { o[nd][0] = 0; o[nd][1] = 0; o[nd][2] = 0; o[nd][3] = 0; }
  float m_r[4] = {-1e30f, -1e30f, -1e30f, -1e30f};
  float l_r[4] = {0.f, 0.f, 0.f, 0.f};

  const int* idxbase = idxs + (size_t)(qrow0 + lhi * 4) * 1024;
  char* pl = (char*)&plds[w][0];

  for (int jt = 0; jt < 16; ++jt) {
    const int j0 = jt * 64;
    // ---- S = Q K^T  (SCALE pre-folded into q) ----
    f32x4 s[4];
#pragma unroll
    for (int nf = 0; nf < 4; ++nf) { s[nf][0] = 0; s[nf][1] = 0; s[nf][2] = 0; s[nf][3] = 0; }
#pragma unroll
    for (int nf = 0; nf < 4; ++nf)
#pragma unroll
      for (int kk = 0; kk < 4; ++kk) {
        bf16x8 kf = *(const bf16x8*)(kp + (size_t)(j0 + nf * 16 + llo) * 128 + kk * 32 + lhi * 8);
        s[nf] = mfma16(qf[kk], kf, s[nf]);
      }
    // ---- bias + online softmax (rows owned within 16-lane group) ----
    float p[4][4], fac[4];
#pragma unroll
    for (int r = 0; r < 4; ++r) {
      const int* ir = idxbase + (size_t)r * 1024 + j0;
      float sv[4];
#pragma unroll
      for (int nf = 0; nf < 4; ++nf)
        sv[nf] = s[nf][r] + biasrow[ir[nf * 16 + llo]];
      float mx = fmaxf(fmaxf(sv[0], sv[1]), fmaxf(sv[2], sv[3]));
#pragma unroll
      for (int off = 1; off < 16; off <<= 1) mx = fmaxf(mx, __shfl_xor(mx, off));
      const float nm = fmaxf(m_r[r], mx);
      fac[r] = __expf(m_r[r] - nm);
      float sum = 0.f;
#pragma unroll
      for (int nf = 0; nf < 4; ++nf) { p[nf][r] = __expf(sv[nf] - nm); sum += p[nf][r]; }
#pragma unroll
      for (int off = 1; off < 16; off <<= 1) sum += __shfl_xor(sum, off);
      l_r[r] = l_r[r] * fac[r] + sum;
      m_r[r] = nm;
    }
#pragma unroll
    for (int nd = 0; nd < 8; ++nd)
#pragma unroll
      for (int r = 0; r < 4; ++r) o[nd][r] *= fac[r];
    // ---- P -> bf16, swizzled per-wave LDS transpose ----
#pragma unroll
    for (int r = 0; r < 4; ++r) {
      const int row = lhi * 4 + r;
      const int sw  = (row & 7) << 4;
#pragma unroll
      for (int nf = 0; nf < 4; ++nf) {
        const int colb = (nf * 16 + llo) * 2;
        *(unsigned short*)(pl + row * 128 + (colb ^ sw)) = f2bf(p[nf][r]);
      }
    }
    // ---- O += P V  (V read from vT: contiguous along kv index) ----
#pragma unroll
    for (int kk2 = 0; kk2 < 2; ++kk2) {
      const int pb = (kk2 * 64 + lhi * 16) ^ ((llo & 7) << 4);
      bf16x8 pa = *(const bf16x8*)(pl + llo * 128 + pb);
#pragma unroll
      for (int nd = 0; nd < 8; ++nd) {
        bf16x8 vf = *(const bf16x8*)(vp + (size_t)(nd * 16 + llo) * 1024 + j0 + kk2 * 32 + lhi * 8);
        o[nd] = mfma16(pa, vf, o[nd]);
      }
    }
  }
  // ---- normalize + write attn_out[b][n][h*128+d] ----
  float inv[4];
#pragma unroll
  for (int r = 0; r < 4; ++r) inv[r] = 1.f / l_r[r];
  const size_t obase = (size_t)b * 1024 * 2048 + (size_t)h * 128;
#pragma unroll
  for (int nd = 0; nd < 8; ++nd)
#pragma unroll
    for (int r = 0; r < 4; ++r)
      aout[obase + (size_t)(qrow0 + lhi * 4 + r) * 2048 + nd * 16 + llo] =
          f2bf(o[nd][r] * inv[r]);
}

// ---------------------------------------------------------------------------
extern "C" void kernel_launch(void* const* d_in, const int* in_sizes, int n_in,
                              void* d_out, int out_size, void* d_ws, size_t ws_size,
                              hipStream_t stream)
{
  const float* x      = (const float*)d_in[0];
  const float* ln_g   = (const float*)d_in[1];
  const float* ln_b   = (const float*)d_in[2];
  const float* qkv_w  = (const float*)d_in[3];
  const float* qkv_b  = (const float*)d_in[4];
  const float* proj_w = (const float*)d_in[5];
  const float* proj_b = (const float*)d_in[6];
  const float* ab     = (const float*)d_in[7];
  const int*   bidx   = (const int*)d_in[8];
  float* out = (float*)d_out;
  char* ws = (char*)d_ws;

  unsigned short* xn = (unsigned short*)(ws);                             // 64 MiB; reused as attn_out
  unsigned short* wt = (unsigned short*)(ws + (size_t)64  * 1024 * 1024); // 24 MiB; qkv_wt then proj_wt
  unsigned short* qb = (unsigned short*)(ws + (size_t)88  * 1024 * 1024); // 64 MiB
  unsigned short* kb = (unsigned short*)(ws + (size_t)152 * 1024 * 1024); // 64 MiB
  unsigned short* vb = (unsigned short*)(ws + (size_t)216 * 1024 * 1024); // 64 MiB
  const int n_off = in_sizes[7] / 16;   // = 1024

  ln_kernel<<<16384, 256, 0, stream>>>(x, ln_g, ln_b, xn);
  wtrans<<<dim3(6144 / 32, 2048 / 32), 256, 0, stream>>>(qkv_w, wt, 2048, 6144);
  gemm_nt<0><<<dim3(48, 128), 256, 0, stream>>>(xn, wt, qkv_b, qb, kb, vb, 2048, 6144);
  wtrans<<<dim3(2048 / 32, 2048 / 32), 256, 0, stream>>>(proj_w, wt, 2048, 2048);
  attn_kernel<<<4096, 256, 0, stream>>>(qb, kb, vb, ab, bidx, xn, n_off);
  gemm_nt<1><<<dim3(16, 128), 256, 0, stream>>>(xn, wt, proj_b, out, nullptr, nullptr, 2048, 2048);
}

// Round 2
// 1801.738 us; speedup vs baseline: 1.1230x; 1.1230x over previous
//
#include <hip/hip_runtime.h>

// ---------------------------------------------------------------------------
// Fused LeViT-attention block for MI355X (gfx950).
// LN -> QKV GEMM (bf16 MFMA) -> flash attn w/ computed rel-pos bias -> proj.
// Workspace (280 MiB, proven):
//   [0,64Mi)    xn bf16 [16384][2048]  (reused as attn_out)
//   [64,88Mi)   qkv_wt bf16 (then proj_wt)
//   [88,152Mi)  q bf16 [b][h][n][d] (pre-scaled)
//   [152,216Mi) k bf16 [b][h][n][d]
//   [216,280Mi) vT bf16 [b][h][d][n]
// ---------------------------------------------------------------------------

typedef __attribute__((ext_vector_type(4))) float          f32x4;
typedef __attribute__((ext_vector_type(8))) short          bf16x8;
typedef __attribute__((ext_vector_type(8))) unsigned short u16x8;
typedef __attribute__((ext_vector_type(4))) unsigned short u16x4;

#define DEV __device__ __forceinline__

DEV unsigned short f2bf(float f) {
  union { float f; unsigned int u; } v; v.f = f;
  unsigned int r = v.u + 0x7fffu + ((v.u >> 16) & 1u);   // RNE
  return (unsigned short)(r >> 16);
}

DEV f32x4 mfma16(bf16x8 a, bf16x8 b, f32x4 c) {
  return __builtin_amdgcn_mfma_f32_16x16x32_bf16(a, b, c, 0, 0, 0);
}

#define GLD_LDS16(g, l) __builtin_amdgcn_global_load_lds(                      \
    (const __attribute__((address_space(1))) void*)(g),                        \
    (__attribute__((address_space(3))) void*)(l), 16, 0, 0)

// ---------------------------------------------------------------------------
// LayerNorm: one block per row (2048 elems), fp32 in -> bf16 out.
// ---------------------------------------------------------------------------
__global__ __launch_bounds__(256) void ln_kernel(
    const float* __restrict__ x, const float* __restrict__ gam,
    const float* __restrict__ bet, unsigned short* __restrict__ xn)
{
  const int row = blockIdx.x;
  const int t   = threadIdx.x;
  const f32x4* xr = (const f32x4*)(x + (size_t)row * 2048);
  f32x4 v0 = xr[t * 2], v1 = xr[t * 2 + 1];
  float s = 0.f, ss = 0.f;
#pragma unroll
  for (int i = 0; i < 4; ++i) { s += v0[i]; ss += v0[i] * v0[i]; }
#pragma unroll
  for (int i = 0; i < 4; ++i) { s += v1[i]; ss += v1[i] * v1[i]; }
#pragma unroll
  for (int off = 32; off; off >>= 1) {
    s  += __shfl_xor(s, off);
    ss += __shfl_xor(ss, off);
  }
  __shared__ float r0[4], r1[4];
  const int w = t >> 6, lane = t & 63;
  if (lane == 0) { r0[w] = s; r1[w] = ss; }
  __syncthreads();
  s  = r0[0] + r0[1] + r0[2] + r0[3];
  ss = r1[0] + r1[1] + r1[2] + r1[3];
  const float mu = s * (1.f / 2048.f);
  const float rs = rsqrtf(ss * (1.f / 2048.f) - mu * mu + 1e-5f);
  const f32x4* gr = (const f32x4*)gam;
  const f32x4* br = (const f32x4*)bet;
  f32x4 g0 = gr[t * 2], g1 = gr[t * 2 + 1];
  f32x4 b0 = br[t * 2], b1 = br[t * 2 + 1];
  u16x8 o;
#pragma unroll
  for (int i = 0; i < 4; ++i) o[i]     = f2bf((v0[i] - mu) * rs * g0[i] + b0[i]);
#pragma unroll
  for (int i = 0; i < 4; ++i) o[4 + i] = f2bf((v1[i] - mu) * rs * g1[i] + b1[i]);
  *(u16x8*)(xn + (size_t)row * 2048 + t * 8) = o;
}

// ---------------------------------------------------------------------------
// Weight transpose + fp32->bf16: W[K][C] -> Wt[C][K]. 32x32 LDS tiles.
// ---------------------------------------------------------------------------
__global__ __launch_bounds__(256) void wtrans(
    const float* __restrict__ W, unsigned short* __restrict__ Wt, int K, int C)
{
  __shared__ float tile[32][33];
  const int c0 = blockIdx.x * 32, k0 = blockIdx.y * 32;
  const int t = threadIdx.x;
  const int r8 = t >> 5, c32 = t & 31;
#pragma unroll
  for (int i = 0; i < 4; ++i)
    tile[i * 8 + r8][c32] = W[(size_t)(k0 + i * 8 + r8) * C + c0 + c32];
  __syncthreads();
#pragma unroll
  for (int i = 0; i < 4; ++i)
    Wt[(size_t)(c0 + i * 8 + r8) * K + k0 + c32] = f2bf(tile[c32][i * 8 + r8]);
}

// ---------------------------------------------------------------------------
// NT GEMM (unchanged from round 1): 128x128 tile, BK=64, 4 waves.
// ---------------------------------------------------------------------------
template <int EPI>
__global__ __launch_bounds__(256, 2) void gemm_nt(
    const unsigned short* __restrict__ A, const unsigned short* __restrict__ Wt,
    const float* __restrict__ bias, void* __restrict__ o0,
    void* __restrict__ o1, void* __restrict__ o2, int K, int C)
{
  __shared__ unsigned short lds[2][2][8192];
  const int m0 = blockIdx.y * 128, n0 = blockIdx.x * 128;
  const int tid = threadIdx.x, lane = tid & 63, w = tid >> 6;
  const int lhi = lane >> 4, llo = lane & 15;
  const int wr = w >> 1, wc = w & 1;

  const unsigned short* Ab = A  + (size_t)m0 * K;
  const unsigned short* Bb = Wt + (size_t)n0 * K;

  f32x4 acc[4][4];
#pragma unroll
  for (int i = 0; i < 4; ++i)
#pragma unroll
    for (int j = 0; j < 4; ++j) { acc[i][j][0] = 0; acc[i][j][1] = 0; acc[i][j][2] = 0; acc[i][j][3] = 0; }

  auto stage = [&](int kt, int buf) {
    const int k0 = kt * 64;
#pragma unroll
    for (int i = 0; i < 4; ++i) {
      const int c    = w * 4 + i;
      const int row  = c * 8 + (lane >> 3);
      const int colb = (lane & 7) * 16;
      const int scol = (colb ^ ((row & 7) << 4)) >> 1;
      GLD_LDS16(Ab + (size_t)row * K + k0 + scol, &lds[buf][0][c * 512]);
      GLD_LDS16(Bb + (size_t)row * K + k0 + scol, &lds[buf][1][c * 512]);
    }
  };

  stage(0, 0);
  __syncthreads();
  const int nk = K >> 6;
  int cur = 0;
  for (int kt = 0; kt < nk; ++kt) {
    if (kt + 1 < nk) stage(kt + 1, cur ^ 1);
    const char* aL = (const char*)&lds[cur][0][0];
    const char* bL = (const char*)&lds[cur][1][0];
#pragma unroll
    for (int kk = 0; kk < 2; ++kk) {
      const int kb = kk * 64 + lhi * 16;
      bf16x8 af[4], bf[4];
#pragma unroll
      for (int t2 = 0; t2 < 4; ++t2) {
        const int ra = wr * 64 + t2 * 16 + llo;
        af[t2] = *(const bf16x8*)(aL + ra * 128 + (kb ^ ((ra & 7) << 4)));
        const int rb = wc * 64 + t2 * 16 + llo;
        bf[t2] = *(const bf16x8*)(bL + rb * 128 + (kb ^ ((rb & 7) << 4)));
      }
#pragma unroll
      for (int ai = 0; ai < 4; ++ai)
#pragma unroll
        for (int bj = 0; bj < 4; ++bj)
          acc[ai][bj] = mfma16(af[ai], bf[bj], acc[ai][bj]);
    }
    __syncthreads();
    cur ^= 1;
  }

  if (EPI == 0) {
    unsigned short* q  = (unsigned short*)o0;
    unsigned short* kk = (unsigned short*)o1;
    unsigned short* vT = (unsigned short*)o2;
    const int which = n0 >> 11;
    const int h     = (n0 >> 7) & 15;
#pragma unroll
    for (int bj = 0; bj < 4; ++bj) {
      const int c  = n0 + wc * 64 + bj * 16 + llo;
      const float bv = bias[c];
      const int d  = c & 127;
#pragma unroll
      for (int ai = 0; ai < 4; ++ai) {
        const int m = m0 + wr * 64 + ai * 16 + lhi * 4;
        const int b = m >> 10, n = m & 1023;
        if (which == 2) {
          u16x4 pk;
#pragma unroll
          for (int r = 0; r < 4; ++r) pk[r] = f2bf(acc[ai][bj][r] + bv);
          *(u16x4*)(vT + ((size_t)(b * 16 + h) * 128 + d) * 1024 + n) = pk;
        } else {
          unsigned short* dst = (which == 0) ? q : kk;
          const float sc = (which == 0) ? 0.08838834764831845f : 1.0f;
#pragma unroll
          for (int r = 0; r < 4; ++r)
            dst[((size_t)(b * 16 + h) * 1024 + n + r) * 128 + d] =
                f2bf((acc[ai][bj][r] + bv) * sc);
        }
      }
    }
  } else {
    float* fo = (float*)o0;
#pragma unroll
    for (int bj = 0; bj < 4; ++bj) {
      const int c  = n0 + wc * 64 + bj * 16 + llo;
      const float bv = bias[c];
#pragma unroll
      for (int ai = 0; ai < 4; ++ai) {
        const int m = m0 + wr * 64 + ai * 16 + lhi * 4;
#pragma unroll
        for (int r = 0; r < 4; ++r)
          fo[(size_t)(m + r) * C + c] = acc[ai][bj][r] + bv;
      }
    }
  }
}

// ---------------------------------------------------------------------------
// Flash attention v2.
//   Grid: 2048 blocks (XCD-swizzled) = (b,h) x 8 q-tiles; 4 waves x 32 q-rows.
//   K tile [64 j][128 d] staged in LDS (dbuf, global_load_lds, XOR swizzle).
//   V read direct from vT global (L2-resident; independent loads hide).
//   Bias computed arithmetically: idx[i][j] == |ri-rj|*32 + |ci-cj|
//   (offsets dict is first-occurrence row-major => identity mapping), value
//   gathered from L1-resident biases[h][.] (4 KB).
// ---------------------------------------------------------------------------
__global__ __launch_bounds__(256) void attn2(
    const unsigned short* __restrict__ q, const unsigned short* __restrict__ k,
    const unsigned short* __restrict__ vT, const float* __restrict__ biases,
    unsigned short* __restrict__ aout, int n_off)
{
  __shared__ unsigned short kt[2][8192];   // [buf][row r2=j*2+dh][64 elems]
  __shared__ unsigned short pl[4][2048];   // per-wave P: 32 rows x 64, swizzled

  const int bid0 = blockIdx.x;
  const int id = ((bid0 & 7) << 8) + (bid0 >> 3);   // XCD-contiguous (2048%8==0)
  const int qt = id & 7, bh = id >> 3;
  const int h = bh & 15, b = bh >> 4;
  const int tid = threadIdx.x, lane = tid & 63, w = tid >> 6;
  const int lhi = lane >> 4, llo = lane & 15;

  const size_t hd = (size_t)bh * (1024 * 128);
  const unsigned short* qp = q  + hd;
  const unsigned short* kp = k  + hd;
  const unsigned short* vp = vT + hd;          // [128][1024]
  const float* brow = biases + (size_t)h * n_off;
  const int qbase = qt * 128 + w * 32;

  // Q fragments in registers (32 rows x 128 d)
  bf16x8 qf[2][4];
#pragma unroll
  for (int g = 0; g < 2; ++g)
#pragma unroll
    for (int kk = 0; kk < 4; ++kk)
      qf[g][kk] = *(const bf16x8*)(qp + (size_t)(qbase + g * 16 + llo) * 128 + kk * 32 + lhi * 8);

  // per-owned-row grid coords for bias index math
  int qr[2][4], qc[2][4];
#pragma unroll
  for (int g = 0; g < 2; ++g)
#pragma unroll
    for (int r = 0; r < 4; ++r) {
      const int qrow = qbase + g * 16 + lhi * 4 + r;
      qr[g][r] = qrow >> 5; qc[g][r] = qrow & 31;
    }

  f32x4 o[2][8];
#pragma unroll
  for (int g = 0; g < 2; ++g)
#pragma unroll
    for (int nd = 0; nd < 8; ++nd) { o[g][nd][0] = 0; o[g][nd][1] = 0; o[g][nd][2] = 0; o[g][nd][3] = 0; }
  float m_[2][4] = {{-1e30f, -1e30f, -1e30f, -1e30f}, {-1e30f, -1e30f, -1e30f, -1e30f}};
  float l_[2][4] = {{0.f, 0.f, 0.f, 0.f}, {0.f, 0.f, 0.f, 0.f}};

  auto stage = [&](int jt, int buf) {
    const int j0g = jt << 6;
#pragma unroll
    for (int i = 0; i < 4; ++i) {
      const int c  = w * 4 + i;             // chunk 0..15 (1 KB each)
      const int r2 = c * 8 + (lane >> 3);   // LDS row (j*2+dh)
      const int cb = (lane & 7) * 16;       // linear byte col
      const int j  = r2 >> 1, dh = r2 & 1;
      const int sc = (cb ^ ((j & 7) << 4)) >> 1;   // pre-swizzled src elem
      GLD_LDS16(kp + (size_t)(j0g + j) * 128 + dh * 64 + sc, &kt[buf][c * 512]);
    }
  };

  stage(0, 0);
  __syncthreads();

  char* plw = (char*)&pl[w][0];
  int cur = 0;
  for (int jt = 0; jt < 16; ++jt) {
    const int j0 = jt << 6;
    if (jt < 15) stage(jt + 1, cur ^ 1);

    // ---- bias values: computed index, L1-resident gather (issued early) ----
    int rj[4], cj[4];
#pragma unroll
    for (int nf = 0; nf < 4; ++nf) {
      const int j = j0 + nf * 16 + llo;
      rj[nf] = j >> 5; cj[nf] = j & 31;
    }
    float bv[2][4][4];
#pragma unroll
    for (int g = 0; g < 2; ++g)
#pragma unroll
      for (int r = 0; r < 4; ++r)
#pragma unroll
        for (int nf = 0; nf < 4; ++nf) {
          const int dr = qr[g][r] - rj[nf], dc = qc[g][r] - cj[nf];
          const int bi = (dr < 0 ? -dr : dr) * 32 + (dc < 0 ? -dc : dc);
          bv[g][r][nf] = brow[bi];
        }

    // ---- S = Q K^T from LDS (swizzled, conflict-free) ----
    const char* kb_ = (const char*)&kt[cur][0];
    f32x4 s[2][4];
#pragma unroll
    for (int g = 0; g < 2; ++g)
#pragma unroll
      for (int nf = 0; nf < 4; ++nf) { s[g][nf][0] = 0; s[g][nf][1] = 0; s[g][nf][2] = 0; s[g][nf][3] = 0; }
#pragma unroll
    for (int nf = 0; nf < 4; ++nf) {
      const int j = nf * 16 + llo;
#pragma unroll
      for (int kk = 0; kk < 4; ++kk) {
        const int d  = kk * 32 + lhi * 8;
        const int r2 = (j << 1) | (d >> 6);
        bf16x8 kf = *(const bf16x8*)(kb_ + r2 * 128 + (((d & 63) * 2) ^ ((j & 7) << 4)));
        s[0][nf] = mfma16(qf[0][kk], kf, s[0][nf]);
        s[1][nf] = mfma16(qf[1][kk], kf, s[1][nf]);
      }
    }

    // ---- bias add + online softmax (rows in 16-lane groups) ----
#pragma unroll
    for (int g = 0; g < 2; ++g)
#pragma unroll
      for (int r = 0; r < 4; ++r) {
        float sv[4];
#pragma unroll
        for (int nf = 0; nf < 4; ++nf) sv[nf] = s[g][nf][r] + bv[g][r][nf];
        float mx = fmaxf(fmaxf(sv[0], sv[1]), fmaxf(sv[2], sv[3]));
#pragma unroll
        for (int off = 1; off < 16; off <<= 1) mx = fmaxf(mx, __shfl_xor(mx, off));
        const float nm = fmaxf(m_[g][r], mx);
        const float fac = __expf(m_[g][r] - nm);
        float p[4], sum = 0.f;
#pragma unroll
        for (int nf = 0; nf < 4; ++nf) { p[nf] = __expf(sv[nf] - nm); sum += p[nf]; }
#pragma unroll
        for (int off = 1; off < 16; off <<= 1) sum += __shfl_xor(sum, off);
        l_[g][r] = l_[g][r] * fac + sum;
        m_[g][r] = nm;
        const int row = g * 16 + lhi * 4 + r;
        const int sw  = (row & 7) << 4;
#pragma unroll
        for (int nf = 0; nf < 4; ++nf)
          *(unsigned short*)(plw + row * 128 + (((nf * 16 + llo) * 2) ^ sw)) = f2bf(p[nf]);
#pragma unroll
        for (int nd = 0; nd < 8; ++nd) o[g][nd][r] *= fac;
      }

    // ---- O += P V  (P from per-wave LDS; V direct from global vT) ----
#pragma unroll
    for (int kk2 = 0; kk2 < 2; ++kk2) {
      bf16x8 pa[2];
#pragma unroll
      for (int g = 0; g < 2; ++g) {
        const int row = g * 16 + llo;
        pa[g] = *(const bf16x8*)(plw + row * 128 + ((kk2 * 64 + lhi * 16) ^ ((row & 7) << 4)));
      }
#pragma unroll
      for (int nd = 0; nd < 8; ++nd) {
        const int d = nd * 16 + llo;
        bf16x8 vf = *(const bf16x8*)(vp + (size_t)d * 1024 + j0 + kk2 * 32 + lhi * 8);
        o[0][nd] = mfma16(pa[0], vf, o[0][nd]);
        o[1][nd] = mfma16(pa[1], vf, o[1][nd]);
      }
    }
    __syncthreads();
    cur ^= 1;
  }

  // ---- normalize + write attn_out[b][n][h*128+d] ----
  float inv[2][4];
#pragma unroll
  for (int g = 0; g < 2; ++g)
#pragma unroll
    for (int r = 0; r < 4; ++r) inv[g][r] = 1.f / l_[g][r];
  const size_t obase = (size_t)b * 1024 * 2048 + (size_t)h * 128;
#pragma unroll
  for (int g = 0; g < 2; ++g)
#pragma unroll
    for (int nd = 0; nd < 8; ++nd)
#pragma unroll
      for (int r = 0; r < 4; ++r)
        aout[obase + (size_t)(qbase + g * 16 + lhi * 4 + r) * 2048 + nd * 16 + llo] =
            f2bf(o[g][nd][r] * inv[g][r]);
}

// ---------------------------------------------------------------------------
extern "C" void kernel_launch(void* const* d_in, const int* in_sizes, int n_in,
                              void* d_out, int out_size, void* d_ws, size_t ws_size,
                              hipStream_t stream)
{
  const float* x      = (const float*)d_in[0];
  const float* ln_g   = (const float*)d_in[1];
  const float* ln_b   = (const float*)d_in[2];
  const float* qkv_w  = (const float*)d_in[3];
  const float* qkv_b  = (const float*)d_in[4];
  const float* proj_w = (const float*)d_in[5];
  const float* proj_b = (const float*)d_in[6];
  const float* ab     = (const float*)d_in[7];
  float* out = (float*)d_out;
  char* ws = (char*)d_ws;

  unsigned short* xn = (unsigned short*)(ws);                             // 64 MiB; reused as attn_out
  unsigned short* wt = (unsigned short*)(ws + (size_t)64  * 1024 * 1024); // 24 MiB
  unsigned short* qb = (unsigned short*)(ws + (size_t)88  * 1024 * 1024);
  unsigned short* kb = (unsigned short*)(ws + (size_t)152 * 1024 * 1024);
  unsigned short* vb = (unsigned short*)(ws + (size_t)216 * 1024 * 1024);
  const int n_off = in_sizes[7] / 16;   // = 1024

  ln_kernel<<<16384, 256, 0, stream>>>(x, ln_g, ln_b, xn);
  wtrans<<<dim3(6144 / 32, 2048 / 32), 256, 0, stream>>>(qkv_w, wt, 2048, 6144);
  gemm_nt<0><<<dim3(48, 128), 256, 0, stream>>>(xn, wt, qkv_b, qb, kb, vb, 2048, 6144);
  wtrans<<<dim3(2048 / 32, 2048 / 32), 256, 0, stream>>>(proj_w, wt, 2048, 2048);
  attn2<<<2048, 256, 0, stream>>>(qb, kb, vb, ab, xn, n_off);
  gemm_nt<1><<<dim3(16, 128), 256, 0, stream>>>(xn, wt, proj_b, out, nullptr, nullptr, 2048, 2048);
}

// Round 7
// 1558.878 us; speedup vs baseline: 1.2980x; 1.1558x over previous
//
#include <hip/hip_runtime.h>

// ---------------------------------------------------------------------------
// Fused LeViT-attention block for MI355X (gfx950).
// LN -> QKV GEMM (bf16 MFMA) -> flash attn w/ computed rel-pos bias -> proj.
// Workspace (280 MiB):
//   [0,64Mi)    xn bf16 [16384][2048]  (reused as attn_out)
//   [64,88Mi)   qkv_wt bf16 (then proj_wt)
//   [88,152Mi)  q bf16 [b][h][n][d] (pre-scaled)
//   [152,216Mi) k bf16 [b][h][n][d]
//   [216,280Mi) vT bf16 [b][h][d][n]
// ---------------------------------------------------------------------------

typedef __attribute__((ext_vector_type(4))) float          f32x4;
typedef __attribute__((ext_vector_type(8))) short          bf16x8;
typedef __attribute__((ext_vector_type(8))) unsigned short u16x8;
typedef __attribute__((ext_vector_type(4))) unsigned short u16x4;

#define DEV __device__ __forceinline__

DEV unsigned short f2bf(float f) {
  union { float f; unsigned int u; } v; v.f = f;
  unsigned int r = v.u + 0x7fffu + ((v.u >> 16) & 1u);   // RNE
  return (unsigned short)(r >> 16);
}

DEV f32x4 mfma16(bf16x8 a, bf16x8 b, f32x4 c) {
  return __builtin_amdgcn_mfma_f32_16x16x32_bf16(a, b, c, 0, 0, 0);
}

#define GLD_LDS16(g, l) __builtin_amdgcn_global_load_lds(                      \
    (const __attribute__((address_space(1))) void*)(g),                        \
    (__attribute__((address_space(3))) void*)(l), 16, 0, 0)

// ---------------------------------------------------------------------------
// LayerNorm: one block per row (2048 elems), fp32 in -> bf16 out.
// ---------------------------------------------------------------------------
__global__ __launch_bounds__(256) void ln_kernel(
    const float* __restrict__ x, const float* __restrict__ gam,
    const float* __restrict__ bet, unsigned short* __restrict__ xn)
{
  const int row = blockIdx.x;
  const int t   = threadIdx.x;
  const f32x4* xr = (const f32x4*)(x + (size_t)row * 2048);
  f32x4 v0 = xr[t * 2], v1 = xr[t * 2 + 1];
  float s = 0.f, ss = 0.f;
#pragma unroll
  for (int i = 0; i < 4; ++i) { s += v0[i]; ss += v0[i] * v0[i]; }
#pragma unroll
  for (int i = 0; i < 4; ++i) { s += v1[i]; ss += v1[i] * v1[i]; }
#pragma unroll
  for (int off = 32; off; off >>= 1) {
    s  += __shfl_xor(s, off);
    ss += __shfl_xor(ss, off);
  }
  __shared__ float r0[4], r1[4];
  const int w = t >> 6, lane = t & 63;
  if (lane == 0) { r0[w] = s; r1[w] = ss; }
  __syncthreads();
  s  = r0[0] + r0[1] + r0[2] + r0[3];
  ss = r1[0] + r1[1] + r1[2] + r1[3];
  const float mu = s * (1.f / 2048.f);
  const float rs = rsqrtf(ss * (1.f / 2048.f) - mu * mu + 1e-5f);
  const f32x4* gr = (const f32x4*)gam;
  const f32x4* br = (const f32x4*)bet;
  f32x4 g0 = gr[t * 2], g1 = gr[t * 2 + 1];
  f32x4 b0 = br[t * 2], b1 = br[t * 2 + 1];
  u16x8 o;
#pragma unroll
  for (int i = 0; i < 4; ++i) o[i]     = f2bf((v0[i] - mu) * rs * g0[i] + b0[i]);
#pragma unroll
  for (int i = 0; i < 4; ++i) o[4 + i] = f2bf((v1[i] - mu) * rs * g1[i] + b1[i]);
  *(u16x8*)(xn + (size_t)row * 2048 + t * 8) = o;
}

// ---------------------------------------------------------------------------
// Weight transpose + fp32->bf16: W[K][C] -> Wt[C][K]. 32x32 LDS tiles.
// ---------------------------------------------------------------------------
__global__ __launch_bounds__(256) void wtrans(
    const float* __restrict__ W, unsigned short* __restrict__ Wt, int K, int C)
{
  __shared__ float tile[32][33];
  const int c0 = blockIdx.x * 32, k0 = blockIdx.y * 32;
  const int t = threadIdx.x;
  const int r8 = t >> 5, c32 = t & 31;
#pragma unroll
  for (int i = 0; i < 4; ++i)
    tile[i * 8 + r8][c32] = W[(size_t)(k0 + i * 8 + r8) * C + c0 + c32];
  __syncthreads();
#pragma unroll
  for (int i = 0; i < 4; ++i)
    Wt[(size_t)(c0 + i * 8 + r8) * K + k0 + c32] = f2bf(tile[c32][i * 8 + r8]);
}

// ---------------------------------------------------------------------------
// NT GEMM: 128x128 tile, BK=64, 4 waves.  XCD-aware bijective block swizzle
// (nwg % 8 == 0 for both instantiations): each XCD gets a contiguous y-major
// chunk so A-row panels are reused within one XCD's L2 instead of being
// replicated across all 8.
// ---------------------------------------------------------------------------
template <int EPI>
__global__ __launch_bounds__(256, 2) void gemm_nt(
    const unsigned short* __restrict__ A, const unsigned short* __restrict__ Wt,
    const float* __restrict__ bias, void* __restrict__ o0,
    void* __restrict__ o1, void* __restrict__ o2, int K, int C)
{
  __shared__ unsigned short lds[2][2][8192];
  const int nwg   = gridDim.x * gridDim.y;
  const int chunk = nwg >> 3;
  int flat = blockIdx.y * gridDim.x + blockIdx.x;
  flat = (flat & 7) * chunk + (flat >> 3);          // bijective XCD swizzle
  const int m0 = (flat / gridDim.x) * 128;
  const int n0 = (flat % gridDim.x) * 128;
  const int tid = threadIdx.x, lane = tid & 63, w = tid >> 6;
  const int lhi = lane >> 4, llo = lane & 15;
  const int wr = w >> 1, wc = w & 1;

  const unsigned short* Ab = A  + (size_t)m0 * K;
  const unsigned short* Bb = Wt + (size_t)n0 * K;

  f32x4 acc[4][4];
#pragma unroll
  for (int i = 0; i < 4; ++i)
#pragma unroll
    for (int j = 0; j < 4; ++j) { acc[i][j][0] = 0; acc[i][j][1] = 0; acc[i][j][2] = 0; acc[i][j][3] = 0; }

  auto stage = [&](int kt, int buf) {
    const int k0 = kt * 64;
#pragma unroll
    for (int i = 0; i < 4; ++i) {
      const int c    = w * 4 + i;
      const int row  = c * 8 + (lane >> 3);
      const int colb = (lane & 7) * 16;
      const int scol = (colb ^ ((row & 7) << 4)) >> 1;
      GLD_LDS16(Ab + (size_t)row * K + k0 + scol, &lds[buf][0][c * 512]);
      GLD_LDS16(Bb + (size_t)row * K + k0 + scol, &lds[buf][1][c * 512]);
    }
  };

  stage(0, 0);
  __syncthreads();
  const int nk = K >> 6;
  int cur = 0;
  for (int kt = 0; kt < nk; ++kt) {
    if (kt + 1 < nk) stage(kt + 1, cur ^ 1);
    const char* aL = (const char*)&lds[cur][0][0];
    const char* bL = (const char*)&lds[cur][1][0];
#pragma unroll
    for (int kk = 0; kk < 2; ++kk) {
      const int kb = kk * 64 + lhi * 16;
      bf16x8 af[4], bf[4];
#pragma unroll
      for (int t2 = 0; t2 < 4; ++t2) {
        const int ra = wr * 64 + t2 * 16 + llo;
        af[t2] = *(const bf16x8*)(aL + ra * 128 + (kb ^ ((ra & 7) << 4)));
        const int rb = wc * 64 + t2 * 16 + llo;
        bf[t2] = *(const bf16x8*)(bL + rb * 128 + (kb ^ ((rb & 7) << 4)));
      }
#pragma unroll
      for (int ai = 0; ai < 4; ++ai)
#pragma unroll
        for (int bj = 0; bj < 4; ++bj)
          acc[ai][bj] = mfma16(af[ai], bf[bj], acc[ai][bj]);
    }
    __syncthreads();
    cur ^= 1;
  }

  if (EPI == 0) {
    unsigned short* q  = (unsigned short*)o0;
    unsigned short* kk = (unsigned short*)o1;
    unsigned short* vT = (unsigned short*)o2;
    const int which = n0 >> 11;
    const int h     = (n0 >> 7) & 15;
#pragma unroll
    for (int bj = 0; bj < 4; ++bj) {
      const int c  = n0 + wc * 64 + bj * 16 + llo;
      const float bv = bias[c];
      const int d  = c & 127;
#pragma unroll
      for (int ai = 0; ai < 4; ++ai) {
        const int m = m0 + wr * 64 + ai * 16 + lhi * 4;
        const int b = m >> 10, n = m & 1023;
        if (which == 2) {
          u16x4 pk;
#pragma unroll
          for (int r = 0; r < 4; ++r) pk[r] = f2bf(acc[ai][bj][r] + bv);
          *(u16x4*)(vT + ((size_t)(b * 16 + h) * 128 + d) * 1024 + n) = pk;
        } else {
          unsigned short* dst = (which == 0) ? q : kk;
          const float sc = (which == 0) ? 0.08838834764831845f : 1.0f;
#pragma unroll
          for (int r = 0; r < 4; ++r)
            dst[((size_t)(b * 16 + h) * 1024 + n + r) * 128 + d] =
                f2bf((acc[ai][bj][r] + bv) * sc);
        }
      }
    }
  } else {
    float* fo = (float*)o0;
#pragma unroll
    for (int bj = 0; bj < 4; ++bj) {
      const int c  = n0 + wc * 64 + bj * 16 + llo;
      const float bv = bias[c];
#pragma unroll
      for (int ai = 0; ai < 4; ++ai) {
        const int m = m0 + wr * 64 + ai * 16 + lhi * 4;
#pragma unroll
        for (int r = 0; r < 4; ++r)
          fo[(size_t)(m + r) * C + c] = acc[ai][bj][r] + bv;
      }
    }
  }
}

// ---------------------------------------------------------------------------
// Flash attention v3 (unchanged from round 3 — experiment still unmeasured).
//   Grid: 2048 blocks (XCD-swizzled) = (b,h) x 8 q-tiles; 4 waves x 32 q-rows.
//   K tile [64 j][128 d] double-buffered in LDS (global_load_lds, XOR swizzle).
//   V tile (from vT [128 d][64 j]) single-buffered in LDS, staged at top of
//   each jt, consumed after the mid-iteration barrier (2-barrier structure).
//   Bias row (4 KB) in LDS; index computed arithmetically
//   (idx[i][j] == |ri-rj|*32 + |ci-cj|), gathered at point of use.
// ---------------------------------------------------------------------------
__global__ __launch_bounds__(256) void attn3(
    const unsigned short* __restrict__ q, const unsigned short* __restrict__ k,
    const unsigned short* __restrict__ vT, const float* __restrict__ biases,
    unsigned short* __restrict__ aout, int n_off)
{
  __shared__ unsigned short kt[2][8192];   // [buf][r2 = j*2+dh][64 elems]
  __shared__ unsigned short vt[8192];      // [d][64 j], row-swizzled
  __shared__ unsigned short pl[4][2048];   // per-wave P: 32 rows x 64, swizzled
  __shared__ float brow_s[1024];           // bias row for this head

  const int bid0 = blockIdx.x;
  const int id = ((bid0 & 7) << 8) + (bid0 >> 3);   // XCD-contiguous (2048%8==0)
  const int qt = id & 7, bh = id >> 3;
  const int h = bh & 15, b = bh >> 4;
  const int tid = threadIdx.x, lane = tid & 63, w = tid >> 6;
  const int lhi = lane >> 4, llo = lane & 15;

  const size_t hd = (size_t)bh * (1024 * 128);
  const unsigned short* qp = q  + hd;
  const unsigned short* kp = k  + hd;
  const unsigned short* vp = vT + hd;          // [128][1024]
  const int qbase = qt * 128 + w * 32;

  // bias row -> LDS (n_off = 1024)
  for (int i = tid; i < n_off; i += 256) brow_s[i] = biases[(size_t)h * n_off + i];

  // Q fragments in registers (32 rows x 128 d)
  bf16x8 qf[2][4];
#pragma unroll
  for (int g = 0; g < 2; ++g)
#pragma unroll
    for (int kk = 0; kk < 4; ++kk)
      qf[g][kk] = *(const bf16x8*)(qp + (size_t)(qbase + g * 16 + llo) * 128 + kk * 32 + lhi * 8);

  // per-owned-row grid coords for bias index math
  int qr[2][4], qc[2][4];
#pragma unroll
  for (int g = 0; g < 2; ++g)
#pragma unroll
    for (int r = 0; r < 4; ++r) {
      const int qrow = qbase + g * 16 + lhi * 4 + r;
      qr[g][r] = qrow >> 5; qc[g][r] = qrow & 31;
    }

  f32x4 o[2][8];
#pragma unroll
  for (int g = 0; g < 2; ++g)
#pragma unroll
    for (int nd = 0; nd < 8; ++nd) { o[g][nd][0] = 0; o[g][nd][1] = 0; o[g][nd][2] = 0; o[g][nd][3] = 0; }
  float m_[2][4] = {{-1e30f, -1e30f, -1e30f, -1e30f}, {-1e30f, -1e30f, -1e30f, -1e30f}};
  float l_[2][4] = {{0.f, 0.f, 0.f, 0.f}, {0.f, 0.f, 0.f, 0.f}};

  auto stageK = [&](int jt, int buf) {
    const int j0g = jt << 6;
#pragma unroll
    for (int i = 0; i < 4; ++i) {
      const int c  = w * 4 + i;             // chunk 0..15 (1 KB each)
      const int r2 = c * 8 + (lane >> 3);   // LDS row (j*2+dh)
      const int cb = (lane & 7) * 16;
      const int j  = r2 >> 1, dh = r2 & 1;
      const int sc = (cb ^ ((j & 7) << 4)) >> 1;   // pre-swizzled src elem
      GLD_LDS16(kp + (size_t)(j0g + j) * 128 + dh * 64 + sc, &kt[buf][c * 512]);
    }
  };
  auto stageV = [&](int jt) {
    const int j0g = jt << 6;
#pragma unroll
    for (int i = 0; i < 4; ++i) {
      const int c  = w * 4 + i;             // chunk 0..15, 8 d-rows each
      const int d  = c * 8 + (lane >> 3);
      const int cb = (lane & 7) * 16;
      const int sc = (cb ^ ((d & 7) << 4)) >> 1;
      GLD_LDS16(vp + (size_t)d * 1024 + j0g + sc, &vt[c * 512]);
    }
  };

  stageK(0, 0);
  stageV(0);
  __syncthreads();

  char* plw = (char*)&pl[w][0];
  int cur = 0;
  for (int jt = 0; jt < 16; ++jt) {
    const int j0 = jt << 6;
    if (jt < 15) stageK(jt + 1, cur ^ 1);   // prefetch next K (dbuf)

    // ---- S = Q K^T from LDS ----
    const char* kb_ = (const char*)&kt[cur][0];
    f32x4 s[2][4];
#pragma unroll
    for (int g = 0; g < 2; ++g)
#pragma unroll
      for (int nf = 0; nf < 4; ++nf) { s[g][nf][0] = 0; s[g][nf][1] = 0; s[g][nf][2] = 0; s[g][nf][3] = 0; }
#pragma unroll
    for (int nf = 0; nf < 4; ++nf) {
      const int j = nf * 16 + llo;
#pragma unroll
      for (int kk = 0; kk < 4; ++kk) {
        const int d  = kk * 32 + lhi * 8;
        const int r2 = (j << 1) | (d >> 6);
        bf16x8 kf = *(const bf16x8*)(kb_ + r2 * 128 + (((d & 63) * 2) ^ ((j & 7) << 4)));
        s[0][nf] = mfma16(qf[0][kk], kf, s[0][nf]);
        s[1][nf] = mfma16(qf[1][kk], kf, s[1][nf]);
      }
    }

    // ---- bias (LDS gather, computed index) + online softmax + P write ----
    int rj[4], cj[4];
#pragma unroll
    for (int nf = 0; nf < 4; ++nf) {
      const int j = j0 + nf * 16 + llo;
      rj[nf] = j >> 5; cj[nf] = j & 31;
    }
#pragma unroll
    for (int g = 0; g < 2; ++g)
#pragma unroll
      for (int r = 0; r < 4; ++r) {
        float sv[4];
#pragma unroll
        for (int nf = 0; nf < 4; ++nf) {
          const int dr = qr[g][r] - rj[nf], dc = qc[g][r] - cj[nf];
          const int bi = (dr < 0 ? -dr : dr) * 32 + (dc < 0 ? -dc : dc);
          sv[nf] = s[g][nf][r] + brow_s[bi];
        }
        float mx = fmaxf(fmaxf(sv[0], sv[1]), fmaxf(sv[2], sv[3]));
#pragma unroll
        for (int off = 1; off < 16; off <<= 1) mx = fmaxf(mx, __shfl_xor(mx, off));
        const float nm = fmaxf(m_[g][r], mx);
        const float fac = __expf(m_[g][r] - nm);
        float p[4], sum = 0.f;
#pragma unroll
        for (int nf = 0; nf < 4; ++nf) { p[nf] = __expf(sv[nf] - nm); sum += p[nf]; }
#pragma unroll
        for (int off = 1; off < 16; off <<= 1) sum += __shfl_xor(sum, off);
        l_[g][r] = l_[g][r] * fac + sum;
        m_[g][r] = nm;
        const int row = g * 16 + lhi * 4 + r;
        const int sw  = (row & 7) << 4;
#pragma unroll
        for (int nf = 0; nf < 4; ++nf)
          *(unsigned short*)(plw + row * 128 + (((nf * 16 + llo) * 2) ^ sw)) = f2bf(p[nf]);
#pragma unroll
        for (int nd = 0; nd < 8; ++nd) o[g][nd][r] *= fac;
      }

    // barrier 1: V[jt] (and K[jt+1]) staging complete; P visible (per-wave anyway)
    __syncthreads();

    // ---- O += P V  (P and V both from LDS) ----
    const char* vb_ = (const char*)&vt[0];
#pragma unroll
    for (int kk2 = 0; kk2 < 2; ++kk2) {
      bf16x8 pa[2];
#pragma unroll
      for (int g = 0; g < 2; ++g) {
        const int row = g * 16 + llo;
        pa[g] = *(const bf16x8*)(plw + row * 128 + ((kk2 * 64 + lhi * 16) ^ ((row & 7) << 4)));
      }
#pragma unroll
      for (int nd = 0; nd < 8; ++nd) {
        const int d = nd * 16 + llo;
        bf16x8 vf = *(const bf16x8*)(vb_ + d * 128 + ((kk2 * 64 + lhi * 16) ^ ((d & 7) << 4)));
        o[0][nd] = mfma16(pa[0], vf, o[0][nd]);
        o[1][nd] = mfma16(pa[1], vf, o[1][nd]);
      }
    }

    // barrier 2: all V reads done before next iteration's stageV overwrites
    __syncthreads();
    if (jt < 15) stageV(jt + 1);
    cur ^= 1;
  }

  // ---- normalize + write attn_out[b][n][h*128+d] ----
  float inv[2][4];
#pragma unroll
  for (int g = 0; g < 2; ++g)
#pragma unroll
    for (int r = 0; r < 4; ++r) inv[g][r] = 1.f / l_[g][r];
  const size_t obase = (size_t)b * 1024 * 2048 + (size_t)h * 128;
#pragma unroll
  for (int g = 0; g < 2; ++g)
#pragma unroll
    for (int nd = 0; nd < 8; ++nd)
#pragma unroll
      for (int r = 0; r < 4; ++r)
        aout[obase + (size_t)(qbase + g * 16 + lhi * 4 + r) * 2048 + nd * 16 + llo] =
            f2bf(o[g][nd][r] * inv[g][r]);
}

// ---------------------------------------------------------------------------
extern "C" void kernel_launch(void* const* d_in, const int* in_sizes, int n_in,
                              void* d_out, int out_size, void* d_ws, size_t ws_size,
                              hipStream_t stream)
{
  const float* x      = (const float*)d_in[0];
  const float* ln_g   = (const float*)d_in[1];
  const float* ln_b   = (const float*)d_in[2];
  const float* qkv_w  = (const float*)d_in[3];
  const float* qkv_b  = (const float*)d_in[4];
  const float* proj_w = (const float*)d_in[5];
  const float* proj_b = (const float*)d_in[6];
  const float* ab     = (const float*)d_in[7];
  float* out = (float*)d_out;
  char* ws = (char*)d_ws;

  unsigned short* xn = (unsigned short*)(ws);                             // 64 MiB; reused as attn_out
  unsigned short* wt = (unsigned short*)(ws + (size_t)64  * 1024 * 1024); // 24 MiB
  unsigned short* qb = (unsigned short*)(ws + (size_t)88  * 1024 * 1024);
  unsigned short* kb = (unsigned short*)(ws + (size_t)152 * 1024 * 1024);
  unsigned short* vb = (unsigned short*)(ws + (size_t)216 * 1024 * 1024);
  const int n_off = in_sizes[7] / 16;   // = 1024

  ln_kernel<<<16384, 256, 0, stream>>>(x, ln_g, ln_b, xn);
  wtrans<<<dim3(6144 / 32, 2048 / 32), 256, 0, stream>>>(qkv_w, wt, 2048, 6144);
  gemm_nt<0><<<dim3(48, 128), 256, 0, stream>>>(xn, wt, qkv_b, qb, kb, vb, 2048, 6144);
  wtrans<<<dim3(2048 / 32, 2048 / 32), 256, 0, stream>>>(proj_w, wt, 2048, 2048);
  attn3<<<2048, 256, 0, stream>>>(qb, kb, vb, ab, xn, n_off);
  gemm_nt<1><<<dim3(16, 128), 256, 0, stream>>>(xn, wt, proj_b, out, nullptr, nullptr, 2048, 2048);
}

// Round 8
// 1326.403 us; speedup vs baseline: 1.5254x; 1.1753x over previous
//
#include <hip/hip_runtime.h>

// ---------------------------------------------------------------------------
// Fused LeViT-attention block for MI355X (gfx950).
// LN -> QKV GEMM (bf16 MFMA) -> flash attn (32x32 swapped-QKT, in-reg softmax)
// -> proj GEMM.
// Workspace (280 MiB):
//   [0,64Mi)    xn bf16 [16384][2048]  (reused as attn_out)
//   [64,88Mi)   qkv_wt bf16 (then proj_wt)
//   [88,152Mi)  q bf16 [b][h][n][d] (pre-scaled)
//   [152,216Mi) k bf16 [b][h][n][d]
//   [216,280Mi) vT bf16 [b][h][d][n]
// ---------------------------------------------------------------------------

typedef __attribute__((ext_vector_type(4)))  float          f32x4;
typedef __attribute__((ext_vector_type(16))) float          f32x16;
typedef __attribute__((ext_vector_type(8)))  short          bf16x8;
typedef __attribute__((ext_vector_type(8)))  unsigned short u16x8;
typedef __attribute__((ext_vector_type(4)))  unsigned short u16x4;

#define DEV __device__ __forceinline__

DEV unsigned short f2bf(float f) {
  union { float f; unsigned int u; } v; v.f = f;
  unsigned int r = v.u + 0x7fffu + ((v.u >> 16) & 1u);   // RNE
  return (unsigned short)(r >> 16);
}

DEV f32x4 mfma16(bf16x8 a, bf16x8 b, f32x4 c) {
  return __builtin_amdgcn_mfma_f32_16x16x32_bf16(a, b, c, 0, 0, 0);
}
DEV f32x16 mfma32(bf16x8 a, bf16x8 b, f32x16 c) {
  return __builtin_amdgcn_mfma_f32_32x32x16_bf16(a, b, c, 0, 0, 0);
}

#define GLD_LDS16(g, l) __builtin_amdgcn_global_load_lds(                      \
    (const __attribute__((address_space(1))) void*)(g),                        \
    (__attribute__((address_space(3))) void*)(l), 16, 0, 0)

// ---------------------------------------------------------------------------
// LayerNorm: one block per row (2048 elems), fp32 in -> bf16 out.
// ---------------------------------------------------------------------------
__global__ __launch_bounds__(256) void ln_kernel(
    const float* __restrict__ x, const float* __restrict__ gam,
    const float* __restrict__ bet, unsigned short* __restrict__ xn)
{
  const int row = blockIdx.x;
  const int t   = threadIdx.x;
  const f32x4* xr = (const f32x4*)(x + (size_t)row * 2048);
  f32x4 v0 = xr[t * 2], v1 = xr[t * 2 + 1];
  float s = 0.f, ss = 0.f;
#pragma unroll
  for (int i = 0; i < 4; ++i) { s += v0[i]; ss += v0[i] * v0[i]; }
#pragma unroll
  for (int i = 0; i < 4; ++i) { s += v1[i]; ss += v1[i] * v1[i]; }
#pragma unroll
  for (int off = 32; off; off >>= 1) {
    s  += __shfl_xor(s, off);
    ss += __shfl_xor(ss, off);
  }
  __shared__ float r0[4], r1[4];
  const int w = t >> 6, lane = t & 63;
  if (lane == 0) { r0[w] = s; r1[w] = ss; }
  __syncthreads();
  s  = r0[0] + r0[1] + r0[2] + r0[3];
  ss = r1[0] + r1[1] + r1[2] + r1[3];
  const float mu = s * (1.f / 2048.f);
  const float rs = rsqrtf(ss * (1.f / 2048.f) - mu * mu + 1e-5f);
  const f32x4* gr = (const f32x4*)gam;
  const f32x4* br = (const f32x4*)bet;
  f32x4 g0 = gr[t * 2], g1 = gr[t * 2 + 1];
  f32x4 b0 = br[t * 2], b1 = br[t * 2 + 1];
  u16x8 o;
#pragma unroll
  for (int i = 0; i < 4; ++i) o[i]     = f2bf((v0[i] - mu) * rs * g0[i] + b0[i]);
#pragma unroll
  for (int i = 0; i < 4; ++i) o[4 + i] = f2bf((v1[i] - mu) * rs * g1[i] + b1[i]);
  *(u16x8*)(xn + (size_t)row * 2048 + t * 8) = o;
}

// ---------------------------------------------------------------------------
// Weight transpose + fp32->bf16: W[K][C] -> Wt[C][K]. 32x32 LDS tiles.
// ---------------------------------------------------------------------------
__global__ __launch_bounds__(256) void wtrans(
    const float* __restrict__ W, unsigned short* __restrict__ Wt, int K, int C)
{
  __shared__ float tile[32][33];
  const int c0 = blockIdx.x * 32, k0 = blockIdx.y * 32;
  const int t = threadIdx.x;
  const int r8 = t >> 5, c32 = t & 31;
#pragma unroll
  for (int i = 0; i < 4; ++i)
    tile[i * 8 + r8][c32] = W[(size_t)(k0 + i * 8 + r8) * C + c0 + c32];
  __syncthreads();
#pragma unroll
  for (int i = 0; i < 4; ++i)
    Wt[(size_t)(c0 + i * 8 + r8) * K + k0 + c32] = f2bf(tile[c32][i * 8 + r8]);
}

// ---------------------------------------------------------------------------
// NT GEMM: 128x128 tile, BK=64, 4 waves, XCD-aware bijective block swizzle.
// ---------------------------------------------------------------------------
template <int EPI>
__global__ __launch_bounds__(256, 2) void gemm_nt(
    const unsigned short* __restrict__ A, const unsigned short* __restrict__ Wt,
    const float* __restrict__ bias, void* __restrict__ o0,
    void* __restrict__ o1, void* __restrict__ o2, int K, int C)
{
  __shared__ unsigned short lds[2][2][8192];
  const int nwg   = gridDim.x * gridDim.y;
  const int chunk = nwg >> 3;
  int flat = blockIdx.y * gridDim.x + blockIdx.x;
  flat = (flat & 7) * chunk + (flat >> 3);          // bijective XCD swizzle
  const int m0 = (flat / gridDim.x) * 128;
  const int n0 = (flat % gridDim.x) * 128;
  const int tid = threadIdx.x, lane = tid & 63, w = tid >> 6;
  const int lhi = lane >> 4, llo = lane & 15;
  const int wr = w >> 1, wc = w & 1;

  const unsigned short* Ab = A  + (size_t)m0 * K;
  const unsigned short* Bb = Wt + (size_t)n0 * K;

  f32x4 acc[4][4];
#pragma unroll
  for (int i = 0; i < 4; ++i)
#pragma unroll
    for (int j = 0; j < 4; ++j) { acc[i][j][0] = 0; acc[i][j][1] = 0; acc[i][j][2] = 0; acc[i][j][3] = 0; }

  auto stage = [&](int kt, int buf) {
    const int k0 = kt * 64;
#pragma unroll
    for (int i = 0; i < 4; ++i) {
      const int c    = w * 4 + i;
      const int row  = c * 8 + (lane >> 3);
      const int colb = (lane & 7) * 16;
      const int scol = (colb ^ ((row & 7) << 4)) >> 1;
      GLD_LDS16(Ab + (size_t)row * K + k0 + scol, &lds[buf][0][c * 512]);
      GLD_LDS16(Bb + (size_t)row * K + k0 + scol, &lds[buf][1][c * 512]);
    }
  };

  stage(0, 0);
  __syncthreads();
  const int nk = K >> 6;
  int cur = 0;
  for (int kt = 0; kt < nk; ++kt) {
    if (kt + 1 < nk) stage(kt + 1, cur ^ 1);
    const char* aL = (const char*)&lds[cur][0][0];
    const char* bL = (const char*)&lds[cur][1][0];
#pragma unroll
    for (int kk = 0; kk < 2; ++kk) {
      const int kb = kk * 64 + lhi * 16;
      bf16x8 af[4], bf[4];
#pragma unroll
      for (int t2 = 0; t2 < 4; ++t2) {
        const int ra = wr * 64 + t2 * 16 + llo;
        af[t2] = *(const bf16x8*)(aL + ra * 128 + (kb ^ ((ra & 7) << 4)));
        const int rb = wc * 64 + t2 * 16 + llo;
        bf[t2] = *(const bf16x8*)(bL + rb * 128 + (kb ^ ((rb & 7) << 4)));
      }
#pragma unroll
      for (int ai = 0; ai < 4; ++ai)
#pragma unroll
        for (int bj = 0; bj < 4; ++bj)
          acc[ai][bj] = mfma16(af[ai], bf[bj], acc[ai][bj]);
    }
    __syncthreads();
    cur ^= 1;
  }

  if (EPI == 0) {
    unsigned short* q  = (unsigned short*)o0;
    unsigned short* kk = (unsigned short*)o1;
    unsigned short* vT = (unsigned short*)o2;
    const int which = n0 >> 11;
    const int h     = (n0 >> 7) & 15;
#pragma unroll
    for (int bj = 0; bj < 4; ++bj) {
      const int c  = n0 + wc * 64 + bj * 16 + llo;
      const float bv = bias[c];
      const int d  = c & 127;
#pragma unroll
      for (int ai = 0; ai < 4; ++ai) {
        const int m = m0 + wr * 64 + ai * 16 + lhi * 4;
        const int b = m >> 10, n = m & 1023;
        if (which == 2) {
          u16x4 pk;
#pragma unroll
          for (int r = 0; r < 4; ++r) pk[r] = f2bf(acc[ai][bj][r] + bv);
          *(u16x4*)(vT + ((size_t)(b * 16 + h) * 128 + d) * 1024 + n) = pk;
        } else {
          unsigned short* dst = (which == 0) ? q : kk;
          const float sc = (which == 0) ? 0.08838834764831845f : 1.0f;
#pragma unroll
          for (int r = 0; r < 4; ++r)
            dst[((size_t)(b * 16 + h) * 1024 + n + r) * 128 + d] =
                f2bf((acc[ai][bj][r] + bv) * sc);
        }
      }
    }
  } else {
    float* fo = (float*)o0;
#pragma unroll
    for (int bj = 0; bj < 4; ++bj) {
      const int c  = n0 + wc * 64 + bj * 16 + llo;
      const float bv = bias[c];
#pragma unroll
      for (int ai = 0; ai < 4; ++ai) {
        const int m = m0 + wr * 64 + ai * 16 + lhi * 4;
#pragma unroll
        for (int r = 0; r < 4; ++r)
          fo[(size_t)(m + r) * C + c] = acc[ai][bj][r] + bv;
      }
    }
  }
}

// ---------------------------------------------------------------------------
// Flash attention v4: 32x32x16 MFMA, swapped QK^T => lane-local q-row softmax.
//   Grid: 2048 blocks (XCD remap) = (b,h) x 8 q-tiles; 4 waves x 32 q-rows.
//   K,V both double-buffered in LDS (global_load_lds, XOR swizzle),
//   ONE barrier per KV tile.
//   S = mfma32(K, Q): lane(c,hi) holds S[q=c][j=(r&3)+8(r>>2)+4hi (+32js)].
//   Softmax: local tree max + one shfl_xor(32); defer-max (THR=8) skips
//   O-rescale; P packed to bf16 in-register and redistributed to the PV
//   A-fragment layout via shfl_xor(32)+select (no LDS round-trip).
//   Bias idx computed arithmetically: |dr|*32 + |dc| (dr uniform per tile).
// ---------------------------------------------------------------------------
__global__ __launch_bounds__(256) void attn4(
    const unsigned short* __restrict__ q, const unsigned short* __restrict__ k,
    const unsigned short* __restrict__ vT, const float* __restrict__ biases,
    unsigned short* __restrict__ aout, int n_off)
{
  __shared__ unsigned short kt[2][8192];   // [buf][j*2+dh][64 elems], swizzled
  __shared__ unsigned short vt[2][8192];   // [buf][d][64 j], swizzled
  __shared__ float brow_s[1024];

  const int bid0 = blockIdx.x;
  const int id = ((bid0 & 7) << 8) + (bid0 >> 3);   // XCD-contiguous
  const int qt = id & 7, bh = id >> 3;
  const int h = bh & 15, b = bh >> 4;
  const int tid = threadIdx.x, lane = tid & 63, w = tid >> 6;
  const int c = lane & 31, hi = lane >> 5;

  const size_t hd = (size_t)bh * (1024 * 128);
  const unsigned short* qp = q  + hd;
  const unsigned short* kp = k  + hd;
  const unsigned short* vp = vT + hd;          // [128][1024]
  const int qbase = qt * 128 + w * 32;
  const int qrow  = qbase + c;
  const int qru   = qbase >> 5;                // wave-uniform (qbase%32==0)
  const int qc    = c;

  for (int i = tid; i < n_off; i += 256) brow_s[i] = biases[(size_t)h * n_off + i];

  // Q fragments: qf[kd] = Q[qrow][kd*16 + hi*8 + 0..7]  (B-operand, col=c=q)
  bf16x8 qf[8];
#pragma unroll
  for (int kd = 0; kd < 8; ++kd)
    qf[kd] = *(const bf16x8*)(qp + (size_t)qrow * 128 + kd * 16 + hi * 8);

  // adc[r] = |qc - cj(r)|, cj(r) = (r&3)+8*(r>>2)+4*hi  (j mod 32)
  int adc[16];
#pragma unroll
  for (int r = 0; r < 16; ++r) {
    const int cj = (r & 3) + 8 * (r >> 2) + 4 * hi;
    const int d  = qc - cj;
    adc[r] = d < 0 ? -d : d;
  }

  f32x16 o_[4];
#pragma unroll
  for (int ds = 0; ds < 4; ++ds)
#pragma unroll
    for (int r = 0; r < 16; ++r) o_[ds][r] = 0.f;
  float m_ = -1e30f, l_ = 0.f;

  auto stageK = [&](int jt_, int buf) {
    const int j0g = jt_ << 6;
#pragma unroll
    for (int i = 0; i < 4; ++i) {
      const int cc = w * 4 + i;
      const int r2 = cc * 8 + (lane >> 3);
      const int cb = (lane & 7) * 16;
      const int j  = r2 >> 1, dh = r2 & 1;
      const int sc = (cb ^ ((j & 7) << 4)) >> 1;
      GLD_LDS16(kp + (size_t)(j0g + j) * 128 + dh * 64 + sc, &kt[buf][cc * 512]);
    }
  };
  auto stageV = [&](int jt_, int buf) {
    const int j0g = jt_ << 6;
#pragma unroll
    for (int i = 0; i < 4; ++i) {
      const int cc = w * 4 + i;
      const int d  = cc * 8 + (lane >> 3);
      const int cb = (lane & 7) * 16;
      const int sc = (cb ^ ((d & 7) << 4)) >> 1;
      GLD_LDS16(vp + (size_t)d * 1024 + j0g + sc, &vt[buf][cc * 512]);
    }
  };

  stageK(0, 0);
  stageV(0, 0);
  __syncthreads();

  int cur = 0;
  for (int jt = 0; jt < 16; ++jt) {
    if (jt < 15) { stageK(jt + 1, cur ^ 1); stageV(jt + 1, cur ^ 1); }

    // ---- S = K x Q (swapped): D[col=c=q][row=(r&3)+8(r>>2)+4hi = j] ----
    const char* kb_ = (const char*)&kt[cur][0];
    f32x16 s0, s1;
#pragma unroll
    for (int r = 0; r < 16; ++r) { s0[r] = 0.f; s1[r] = 0.f; }
    __builtin_amdgcn_s_setprio(1);
#pragma unroll
    for (int kd = 0; kd < 8; ++kd) {
      const int dlo = kd * 16 + hi * 8;
      const int off = (((dlo & 63) * 2) ^ ((c & 7) << 4));
      bf16x8 kf0 = *(const bf16x8*)(kb_ + (((c)      << 1) | (dlo >> 6)) * 128 + off);
      bf16x8 kf1 = *(const bf16x8*)(kb_ + (((32 + c) << 1) | (dlo >> 6)) * 128 + off);
      s0 = mfma32(kf0, qf[kd], s0);
      s1 = mfma32(kf1, qf[kd], s1);
    }
    __builtin_amdgcn_s_setprio(0);

    // ---- bias add (computed idx, LDS gather) ----
    float sv[2][16];
#pragma unroll
    for (int js = 0; js < 2; ++js) {
      const int drr = qru - (jt * 2 + js);
      const int adr = (drr < 0 ? -drr : drr) * 32;
#pragma unroll
      for (int r = 0; r < 16; ++r)
        sv[js][r] = (js ? s1[r] : s0[r]) + brow_s[adr + adc[r]];
    }

    // ---- online softmax, lane-local row ----
    float mx = sv[0][0];
#pragma unroll
    for (int r = 1; r < 16; ++r) mx = fmaxf(mx, sv[0][r]);
#pragma unroll
    for (int r = 0; r < 16; ++r) mx = fmaxf(mx, sv[1][r]);
    mx = fmaxf(mx, __shfl_xor(mx, 32));

    if (!__all(mx - m_ <= 8.0f)) {       // defer-max: rescale only on growth
      const float nm  = fmaxf(m_, mx);
      const float fac = __expf(m_ - nm);
      m_ = nm;
      l_ *= fac;
#pragma unroll
      for (int r = 0; r < 16; ++r) {
        const float fr = __shfl(fac, (r & 3) + 8 * (r >> 2) + 4 * hi);
#pragma unroll
        for (int ds = 0; ds < 4; ++ds) o_[ds][r] *= fr;
      }
    }

    float sum = 0.f;
#pragma unroll
    for (int js = 0; js < 2; ++js)
#pragma unroll
      for (int r = 0; r < 16; ++r) {
        const float p = __expf(sv[js][r] - m_);
        sv[js][r] = p;
        sum += p;
      }
    sum += __shfl_xor(sum, 32);
    l_ += sum;

    // ---- pack P to bf16 word-pairs: wpk[js][wi] = (p[2wi], p[2wi+1]) ----
    unsigned int wpk[2][8];
#pragma unroll
    for (int js = 0; js < 2; ++js)
#pragma unroll
      for (int wi = 0; wi < 8; ++wi)
        wpk[js][wi] = (unsigned int)f2bf(sv[js][2 * wi]) |
                      ((unsigned int)f2bf(sv[js][2 * wi + 1]) << 16);

    // ---- O += P x V: redistribute P to A-frag via shfl_xor(32)+select ----
    const char* vb_ = (const char*)&vt[cur][0];
    __builtin_amdgcn_s_setprio(1);
#pragma unroll
    for (int kj = 0; kj < 4; ++kj) {
      const int js = kj >> 1, base = (kj & 1) * 4;
      const unsigned int u0 = wpk[js][base + 0], u1 = wpk[js][base + 1];
      const unsigned int u2 = wpk[js][base + 2], u3 = wpk[js][base + 3];
      const unsigned int t0 = __shfl_xor(u0, 32), t1 = __shfl_xor(u1, 32);
      const unsigned int t2 = __shfl_xor(u2, 32), t3 = __shfl_xor(u3, 32);
      union { unsigned int u[4]; bf16x8 v; } af;
      af.u[0] = hi ? t2 : u0;   // j = 8hi + {0,1}
      af.u[1] = hi ? t3 : u1;   // j = 8hi + {2,3}
      af.u[2] = hi ? u2 : t0;   // j = 8hi + {4,5}
      af.u[3] = hi ? u3 : t1;   // j = 8hi + {6,7}
#pragma unroll
      for (int ds = 0; ds < 4; ++ds) {
        const int d = ds * 32 + c;
        bf16x8 vf = *(const bf16x8*)(vb_ + d * 128 + ((kj * 32 + hi * 16) ^ ((d & 7) << 4)));
        o_[ds] = mfma32(af.v, vf, o_[ds]);
      }
    }
    __builtin_amdgcn_s_setprio(0);

    __syncthreads();      // all reads of cur done; next iter stages into cur
    cur ^= 1;
  }

  // ---- normalize + write attn_out[b][n][h*128+d] ----
#pragma unroll
  for (int r = 0; r < 16; ++r) {
    const int qloc = (r & 3) + 8 * (r >> 2) + 4 * hi;
    const float lr = __shfl(l_, qloc);
    const float inv = 1.f / lr;
    const size_t rowb = (size_t)b * 1024 * 2048 + (size_t)(qbase + qloc) * 2048 + h * 128;
#pragma unroll
    for (int ds = 0; ds < 4; ++ds)
      aout[rowb + ds * 32 + c] = f2bf(o_[ds][r] * inv);
  }
}

// ---------------------------------------------------------------------------
extern "C" void kernel_launch(void* const* d_in, const int* in_sizes, int n_in,
                              void* d_out, int out_size, void* d_ws, size_t ws_size,
                              hipStream_t stream)
{
  const float* x      = (const float*)d_in[0];
  const float* ln_g   = (const float*)d_in[1];
  const float* ln_b   = (const float*)d_in[2];
  const float* qkv_w  = (const float*)d_in[3];
  const float* qkv_b  = (const float*)d_in[4];
  const float* proj_w = (const float*)d_in[5];
  const float* proj_b = (const float*)d_in[6];
  const float* ab     = (const float*)d_in[7];
  float* out = (float*)d_out;
  char* ws = (char*)d_ws;

  unsigned short* xn = (unsigned short*)(ws);                             // 64 MiB; reused as attn_out
  unsigned short* wt = (unsigned short*)(ws + (size_t)64  * 1024 * 1024); // 24 MiB
  unsigned short* qb = (unsigned short*)(ws + (size_t)88  * 1024 * 1024);
  unsigned short* kb = (unsigned short*)(ws + (size_t)152 * 1024 * 1024);
  unsigned short* vb = (unsigned short*)(ws + (size_t)216 * 1024 * 1024);
  const int n_off = in_sizes[7] / 16;   // = 1024

  ln_kernel<<<16384, 256, 0, stream>>>(x, ln_g, ln_b, xn);
  wtrans<<<dim3(6144 / 32, 2048 / 32), 256, 0, stream>>>(qkv_w, wt, 2048, 6144);
  gemm_nt<0><<<dim3(48, 128), 256, 0, stream>>>(xn, wt, qkv_b, qb, kb, vb, 2048, 6144);
  wtrans<<<dim3(2048 / 32, 2048 / 32), 256, 0, stream>>>(proj_w, wt, 2048, 2048);
  attn4<<<2048, 256, 0, stream>>>(qb, kb, vb, ab, xn, n_off);
  gemm_nt<1><<<dim3(16, 128), 256, 0, stream>>>(xn, wt, proj_b, out, nullptr, nullptr, 2048, 2048);
}

// Round 10
// 1217.545 us; speedup vs baseline: 1.6618x; 1.0894x over previous
//
#include <hip/hip_runtime.h>

// ---------------------------------------------------------------------------
// Fused LeViT-attention block for MI355X (gfx950).
// LN -> QKV GEMM (256^2 8-phase bf16 MFMA) -> flash attn (32x32 swapped-QKT,
// in-reg softmax) -> proj GEMM.
// Workspace (280 MiB):
//   [0,64Mi)    xn bf16 [16384][2048]  (reused as attn_out)
//   [64,88Mi)   qkv_wt bf16 (then proj_wt)
//   [88,152Mi)  q bf16 [b][h][n][d] (pre-scaled)
//   [152,216Mi) k bf16 [b][h][n][d]
//   [216,280Mi) vT bf16 [b][h][d][n]
// ---------------------------------------------------------------------------

typedef __attribute__((ext_vector_type(4)))  float          f32x4;
typedef __attribute__((ext_vector_type(16))) float          f32x16;
typedef __attribute__((ext_vector_type(8)))  short          bf16x8;
typedef __attribute__((ext_vector_type(8)))  unsigned short u16x8;
typedef __attribute__((ext_vector_type(4)))  unsigned short u16x4;

#define DEV __device__ __forceinline__

DEV unsigned short f2bf(float f) {
  union { float f; unsigned int u; } v; v.f = f;
  unsigned int r = v.u + 0x7fffu + ((v.u >> 16) & 1u);   // RNE
  return (unsigned short)(r >> 16);
}

DEV f32x4 mfma16(bf16x8 a, bf16x8 b, f32x4 c) {
  return __builtin_amdgcn_mfma_f32_16x16x32_bf16(a, b, c, 0, 0, 0);
}
DEV f32x16 mfma32(bf16x8 a, bf16x8 b, f32x16 c) {
  return __builtin_amdgcn_mfma_f32_32x32x16_bf16(a, b, c, 0, 0, 0);
}

#define GLD_LDS16(g, l) __builtin_amdgcn_global_load_lds(                      \
    (const __attribute__((address_space(1))) void*)(g),                        \
    (__attribute__((address_space(3))) void*)(l), 16, 0, 0)

// ---------------------------------------------------------------------------
// LayerNorm: one block per row (2048 elems), fp32 in -> bf16 out.
// ---------------------------------------------------------------------------
__global__ __launch_bounds__(256) void ln_kernel(
    const float* __restrict__ x, const float* __restrict__ gam,
    const float* __restrict__ bet, unsigned short* __restrict__ xn)
{
  const int row = blockIdx.x;
  const int t   = threadIdx.x;
  const f32x4* xr = (const f32x4*)(x + (size_t)row * 2048);
  f32x4 v0 = xr[t * 2], v1 = xr[t * 2 + 1];
  float s = 0.f, ss = 0.f;
#pragma unroll
  for (int i = 0; i < 4; ++i) { s += v0[i]; ss += v0[i] * v0[i]; }
#pragma unroll
  for (int i = 0; i < 4; ++i) { s += v1[i]; ss += v1[i] * v1[i]; }
#pragma unroll
  for (int off = 32; off; off >>= 1) {
    s  += __shfl_xor(s, off);
    ss += __shfl_xor(ss, off);
  }
  __shared__ float r0[4], r1[4];
  const int w = t >> 6, lane = t & 63;
  if (lane == 0) { r0[w] = s; r1[w] = ss; }
  __syncthreads();
  s  = r0[0] + r0[1] + r0[2] + r0[3];
  ss = r1[0] + r1[1] + r1[2] + r1[3];
  const float mu = s * (1.f / 2048.f);
  const float rs = rsqrtf(ss * (1.f / 2048.f) - mu * mu + 1e-5f);
  const f32x4* gr = (const f32x4*)gam;
  const f32x4* br = (const f32x4*)bet;
  f32x4 g0 = gr[t * 2], g1 = gr[t * 2 + 1];
  f32x4 b0 = br[t * 2], b1 = br[t * 2 + 1];
  u16x8 o;
#pragma unroll
  for (int i = 0; i < 4; ++i) o[i]     = f2bf((v0[i] - mu) * rs * g0[i] + b0[i]);
#pragma unroll
  for (int i = 0; i < 4; ++i) o[4 + i] = f2bf((v1[i] - mu) * rs * g1[i] + b1[i]);
  *(u16x8*)(xn + (size_t)row * 2048 + t * 8) = o;
}

// ---------------------------------------------------------------------------
// Weight transpose + fp32->bf16: W[K][C] -> Wt[C][K]. 32x32 LDS tiles.
// ---------------------------------------------------------------------------
__global__ __launch_bounds__(256) void wtrans(
    const float* __restrict__ W, unsigned short* __restrict__ Wt, int K, int C)
{
  __shared__ float tile[32][33];
  const int c0 = blockIdx.x * 32, k0 = blockIdx.y * 32;
  const int t = threadIdx.x;
  const int r8 = t >> 5, c32 = t & 31;
#pragma unroll
  for (int i = 0; i < 4; ++i)
    tile[i * 8 + r8][c32] = W[(size_t)(k0 + i * 8 + r8) * C + c0 + c32];
  __syncthreads();
#pragma unroll
  for (int i = 0; i < 4; ++i)
    Wt[(size_t)(c0 + i * 8 + r8) * K + k0 + c32] = f2bf(tile[c32][i * 8 + r8]);
}

// ---------------------------------------------------------------------------
// NT GEMM, 256x256 tile, BK=64, 8 waves (2Mx4N), 512 threads, 8-phase-style
// schedule: per K-tile 4 phases, each {ds_read quadrant | stage one half-tile
// | barrier | lgkmcnt(0) | 16 MFMA | barrier}; counted vmcnt(4) once per
// K-tile (never 0 mid-loop). XOR-swizzled LDS (pre-swizzled global source).
// XCD-aware bijective block swizzle.
// Half-tile stage map (proven free-before-write by the phase barriers):
//   T.ph1 -> Alo(T+1), T.ph2 -> Ahi(T+1)  (A halves of buf free after ph3)
//   T.ph3 -> Bh0(T+2), T.ph4 -> Bh1(T+2)  (B halves of buf free after ph2)
// ---------------------------------------------------------------------------
template <int EPI>
__global__ __launch_bounds__(512, 2) void gemm_nt(
    const unsigned short* __restrict__ A, const unsigned short* __restrict__ Wt,
    const float* __restrict__ bias, void* __restrict__ o0,
    void* __restrict__ o1, void* __restrict__ o2, int K, int C)
{
  __shared__ unsigned short Al[2][256 * 64];   // [buf][row][64], swizzled
  __shared__ unsigned short Bl[2][256 * 64];

  const int nwg   = gridDim.x * gridDim.y;
  const int chunk = nwg >> 3;
  int flat = blockIdx.y * gridDim.x + blockIdx.x;
  flat = (flat & 7) * chunk + (flat >> 3);          // bijective XCD swizzle
  const int m0 = (flat / gridDim.x) * 256;
  const int n0 = (flat % gridDim.x) * 256;
  const int tid = threadIdx.x, lane = tid & 63, w = tid >> 6;
  const int lhi = lane >> 4, llo = lane & 15;
  const int wr = w >> 2, wc = w & 3;

  const unsigned short* Ab = A  + (size_t)m0 * K;
  const unsigned short* Bb = Wt + (size_t)n0 * K;

  f32x4 acc[8][4];
#pragma unroll
  for (int i = 0; i < 8; ++i)
#pragma unroll
    for (int j = 0; j < 4; ++j) { acc[i][j][0] = 0; acc[i][j][1] = 0; acc[i][j][2] = 0; acc[i][j][3] = 0; }

  // stage one half-tile (128 rows x 64 cols, 2 x 64-row bands, 2 loads/thread)
  auto stageA = [&](int kt, int bufi, int half) {
    const int k0 = kt * 64;
#pragma unroll
    for (int i = 0; i < 2; ++i) {
      const int rbase = half * 128 + i * 64 + w * 8;
      const int row   = rbase + (lane >> 3);
      const int sc    = (((lane & 7) * 16) ^ ((row & 7) << 4)) >> 1;
      GLD_LDS16(Ab + (size_t)row * K + k0 + sc, &Al[bufi][rbase * 64]);
    }
  };
  auto stageB = [&](int kt, int bufi, int half) {
    const int k0 = kt * 64;
#pragma unroll
    for (int i = 0; i < 2; ++i) {
      const int rbase = half * 128 + i * 64 + w * 8;
      const int row   = rbase + (lane >> 3);
      const int sc    = (((lane & 7) * 16) ^ ((row & 7) << 4)) >> 1;
      GLD_LDS16(Bb + (size_t)row * K + k0 + sc, &Bl[bufi][rbase * 64]);
    }
  };

  const int nk = K >> 6;   // 32

  // Prologue: tile0 fully + tile1's B halves; wait tile0 (4 loads stay in flight)
  stageA(0, 0, 0); stageA(0, 0, 1);
  stageB(0, 0, 0); stageB(0, 0, 1);
  stageB(1, 1, 0); stageB(1, 1, 1);
  asm volatile("s_waitcnt vmcnt(4)" ::: "memory");
  __builtin_amdgcn_sched_barrier(0);
  __builtin_amdgcn_s_barrier();

  bf16x8 aq[4][2];   // current qm-quadrant A frags
  bf16x8 bq[4][2];   // full-tile B frags (qn0 read ph1, qn1 read ph2)

  for (int t = 0; t < nk; ++t) {
    const int buf = t & 1;
    const char* aL = (const char*)&Al[buf][0];
    const char* bL = (const char*)&Bl[buf][0];

    // ---------------- phase 1: quadrant (qm0, qn0) ----------------
#pragma unroll
    for (int rr = 0; rr < 4; ++rr)
#pragma unroll
      for (int kk = 0; kk < 2; ++kk) {
        const int ra = wr * 128 + rr * 16 + llo;
        aq[rr][kk] = *(const bf16x8*)(aL + ra * 128 + ((kk * 64 + lhi * 16) ^ ((ra & 7) << 4)));
      }
#pragma unroll
    for (int nn = 0; nn < 2; ++nn)
#pragma unroll
      for (int kk = 0; kk < 2; ++kk) {
        const int rb = wc * 64 + nn * 16 + llo;
        bq[nn][kk] = *(const bf16x8*)(bL + rb * 128 + ((kk * 64 + lhi * 16) ^ ((rb & 7) << 4)));
      }
    if (t + 1 < nk) stageA(t + 1, (t + 1) & 1, 0);
    __builtin_amdgcn_s_barrier();
    asm volatile("s_waitcnt lgkmcnt(0)" ::: "memory");
    __builtin_amdgcn_sched_barrier(0);
    __builtin_amdgcn_s_setprio(1);
#pragma unroll
    for (int rr = 0; rr < 4; ++rr)
#pragma unroll
      for (int nn = 0; nn < 2; ++nn)
#pragma unroll
        for (int kk = 0; kk < 2; ++kk)
          acc[rr][nn] = mfma16(aq[rr][kk], bq[nn][kk], acc[rr][nn]);
    __builtin_amdgcn_s_setprio(0);
    __builtin_amdgcn_s_barrier();

    // ---------------- phase 2: quadrant (qm0, qn1) ----------------
#pragma unroll
    for (int nn = 2; nn < 4; ++nn)
#pragma unroll
      for (int kk = 0; kk < 2; ++kk) {
        const int rb = wc * 64 + nn * 16 + llo;
        bq[nn][kk] = *(const bf16x8*)(bL + rb * 128 + ((kk * 64 + lhi * 16) ^ ((rb & 7) << 4)));
      }
    if (t + 1 < nk) stageA(t + 1, (t + 1) & 1, 1);
    __builtin_amdgcn_s_barrier();
    asm volatile("s_waitcnt lgkmcnt(0)" ::: "memory");
    __builtin_amdgcn_sched_barrier(0);
    __builtin_amdgcn_s_setprio(1);
#pragma unroll
    for (int rr = 0; rr < 4; ++rr)
#pragma unroll
      for (int nn = 2; nn < 4; ++nn)
#pragma unroll
        for (int kk = 0; kk < 2; ++kk)
          acc[rr][nn] = mfma16(aq[rr][kk], bq[nn][kk], acc[rr][nn]);
    __builtin_amdgcn_s_setprio(0);
    __builtin_amdgcn_s_barrier();

    // ---------------- phase 3: quadrant (qm1, qn0) ----------------
#pragma unroll
    for (int rr = 0; rr < 4; ++rr)
#pragma unroll
      for (int kk = 0; kk < 2; ++kk) {
        const int ra = wr * 128 + 64 + rr * 16 + llo;
        aq[rr][kk] = *(const bf16x8*)(aL + ra * 128 + ((kk * 64 + lhi * 16) ^ ((ra & 7) << 4)));
      }
    if (t + 2 < nk) stageB(t + 2, buf, 0);
    __builtin_amdgcn_s_barrier();
    asm volatile("s_waitcnt lgkmcnt(0)" ::: "memory");
    __builtin_amdgcn_sched_barrier(0);
    __builtin_amdgcn_s_setprio(1);
#pragma unroll
    for (int rr = 0; rr < 4; ++rr)
#pragma unroll
      for (int nn = 0; nn < 2; ++nn)
#pragma unroll
        for (int kk = 0; kk < 2; ++kk)
          acc[4 + rr][nn] = mfma16(aq[rr][kk], bq[nn][kk], acc[4 + rr][nn]);
    __builtin_amdgcn_s_setprio(0);
    __builtin_amdgcn_s_barrier();

    // ---------------- phase 4: quadrant (qm1, qn1) ----------------
    if (t + 2 < nk) stageB(t + 2, buf, 1);
    __builtin_amdgcn_s_barrier();
    __builtin_amdgcn_s_setprio(1);
#pragma unroll
    for (int rr = 0; rr < 4; ++rr)
#pragma unroll
      for (int nn = 2; nn < 4; ++nn)
#pragma unroll
        for (int kk = 0; kk < 2; ++kk)
          acc[4 + rr][nn] = mfma16(aq[rr][kk], bq[nn][kk], acc[4 + rr][nn]);
    __builtin_amdgcn_s_setprio(0);
    // counted vmcnt: confirm A halves of tile t+1; leave B halves of t+2 flying
    if (t + 1 < nk) {
      if (t + 2 < nk) asm volatile("s_waitcnt vmcnt(4)" ::: "memory");
      else            asm volatile("s_waitcnt vmcnt(0)" ::: "memory");
      __builtin_amdgcn_sched_barrier(0);
    }
    __builtin_amdgcn_s_barrier();
  }

  if (EPI == 0) {
    unsigned short* q  = (unsigned short*)o0;
    unsigned short* kk = (unsigned short*)o1;
    unsigned short* vT = (unsigned short*)o2;
    const int which = n0 >> 11;          // 256-tile lies in one of q/k/v
#pragma unroll
    for (int n = 0; n < 4; ++n) {
      const int c  = n0 + wc * 64 + n * 16 + llo;
      const float bv = bias[c];
      const int h  = (c >> 7) & 15;
      const int d  = c & 127;
#pragma unroll
      for (int r = 0; r < 8; ++r) {
        const int m = m0 + wr * 128 + r * 16 + lhi * 4;
        const int b = m >> 10, ntok = m & 1023;
        if (which == 2) {
          u16x4 pk;
#pragma unroll
          for (int e = 0; e < 4; ++e) pk[e] = f2bf(acc[r][n][e] + bv);
          *(u16x4*)(vT + ((size_t)(b * 16 + h) * 128 + d) * 1024 + ntok) = pk;
        } else {
          unsigned short* dst = (which == 0) ? q : kk;
          const float sc = (which == 0) ? 0.08838834764831845f : 1.0f;
#pragma unroll
          for (int e = 0; e < 4; ++e)
            dst[((size_t)(b * 16 + h) * 1024 + ntok + e) * 128 + d] =
                f2bf((acc[r][n][e] + bv) * sc);
        }
      }
    }
  } else {
    float* fo = (float*)o0;
#pragma unroll
    for (int n = 0; n < 4; ++n) {
      const int c  = n0 + wc * 64 + n * 16 + llo;
      const float bv = bias[c];
#pragma unroll
      for (int r = 0; r < 8; ++r) {
        const int m = m0 + wr * 128 + r * 16 + lhi * 4;
#pragma unroll
        for (int e = 0; e < 4; ++e)
          fo[(size_t)(m + e) * C + c] = acc[r][n][e] + bv;
      }
    }
  }
}

// ---------------------------------------------------------------------------
// Flash attention v4 (unchanged from round 8): 32x32x16 MFMA, swapped QK^T.
// ---------------------------------------------------------------------------
__global__ __launch_bounds__(256) void attn4(
    const unsigned short* __restrict__ q, const unsigned short* __restrict__ k,
    const unsigned short* __restrict__ vT, const float* __restrict__ biases,
    unsigned short* __restrict__ aout, int n_off)
{
  __shared__ unsigned short kt[2][8192];   // [buf][j*2+dh][64 elems], swizzled
  __shared__ unsigned short vt[2][8192];   // [buf][d][64 j], swizzled
  __shared__ float brow_s[1024];

  const int bid0 = blockIdx.x;
  const int id = ((bid0 & 7) << 8) + (bid0 >> 3);   // XCD-contiguous
  const int qt = id & 7, bh = id >> 3;
  const int h = bh & 15, b = bh >> 4;
  const int tid = threadIdx.x, lane = tid & 63, w = tid >> 6;
  const int c = lane & 31, hi = lane >> 5;

  const size_t hd = (size_t)bh * (1024 * 128);
  const unsigned short* qp = q  + hd;
  const unsigned short* kp = k  + hd;
  const unsigned short* vp = vT + hd;          // [128][1024]
  const int qbase = qt * 128 + w * 32;
  const int qrow  = qbase + c;
  const int qru   = qbase >> 5;                // wave-uniform (qbase%32==0)
  const int qc    = c;

  for (int i = tid; i < n_off; i += 256) brow_s[i] = biases[(size_t)h * n_off + i];

  // Q fragments: qf[kd] = Q[qrow][kd*16 + hi*8 + 0..7]  (B-operand, col=c=q)
  bf16x8 qf[8];
#pragma unroll
  for (int kd = 0; kd < 8; ++kd)
    qf[kd] = *(const bf16x8*)(qp + (size_t)qrow * 128 + kd * 16 + hi * 8);

  // adc[r] = |qc - cj(r)|, cj(r) = (r&3)+8*(r>>2)+4*hi  (j mod 32)
  int adc[16];
#pragma unroll
  for (int r = 0; r < 16; ++r) {
    const int cj = (r & 3) + 8 * (r >> 2) + 4 * hi;
    const int d  = qc - cj;
    adc[r] = d < 0 ? -d : d;
  }

  f32x16 o_[4];
#pragma unroll
  for (int ds = 0; ds < 4; ++ds)
#pragma unroll
    for (int r = 0; r < 16; ++r) o_[ds][r] = 0.f;
  float m_ = -1e30f, l_ = 0.f;

  auto stageK = [&](int jt_, int buf) {
    const int j0g = jt_ << 6;
#pragma unroll
    for (int i = 0; i < 4; ++i) {
      const int cc = w * 4 + i;
      const int r2 = cc * 8 + (lane >> 3);
      const int cb = (lane & 7) * 16;
      const int j  = r2 >> 1, dh = r2 & 1;
      const int sc = (cb ^ ((j & 7) << 4)) >> 1;
      GLD_LDS16(kp + (size_t)(j0g + j) * 128 + dh * 64 + sc, &kt[buf][cc * 512]);
    }
  };
  auto stageV = [&](int jt_, int buf) {
    const int j0g = jt_ << 6;
#pragma unroll
    for (int i = 0; i < 4; ++i) {
      const int cc = w * 4 + i;
      const int d  = cc * 8 + (lane >> 3);
      const int cb = (lane & 7) * 16;
      const int sc = (cb ^ ((d & 7) << 4)) >> 1;
      GLD_LDS16(vp + (size_t)d * 1024 + j0g + sc, &vt[buf][cc * 512]);
    }
  };

  stageK(0, 0);
  stageV(0, 0);
  __syncthreads();

  int cur = 0;
  for (int jt = 0; jt < 16; ++jt) {
    if (jt < 15) { stageK(jt + 1, cur ^ 1); stageV(jt + 1, cur ^ 1); }

    // ---- S = K x Q (swapped): D[col=c=q][row=(r&3)+8(r>>2)+4hi = j] ----
    const char* kb_ = (const char*)&kt[cur][0];
    f32x16 s0, s1;
#pragma unroll
    for (int r = 0; r < 16; ++r) { s0[r] = 0.f; s1[r] = 0.f; }
    __builtin_amdgcn_s_setprio(1);
#pragma unroll
    for (int kd = 0; kd < 8; ++kd) {
      const int dlo = kd * 16 + hi * 8;
      const int off = (((dlo & 63) * 2) ^ ((c & 7) << 4));
      bf16x8 kf0 = *(const bf16x8*)(kb_ + (((c)      << 1) | (dlo >> 6)) * 128 + off);
      bf16x8 kf1 = *(const bf16x8*)(kb_ + (((32 + c) << 1) | (dlo >> 6)) * 128 + off);
      s0 = mfma32(kf0, qf[kd], s0);
      s1 = mfma32(kf1, qf[kd], s1);
    }
    __builtin_amdgcn_s_setprio(0);

    // ---- bias add (computed idx, LDS gather) ----
    float sv[2][16];
#pragma unroll
    for (int js = 0; js < 2; ++js) {
      const int drr = qru - (jt * 2 + js);
      const int adr = (drr < 0 ? -drr : drr) * 32;
#pragma unroll
      for (int r = 0; r < 16; ++r)
        sv[js][r] = (js ? s1[r] : s0[r]) + brow_s[adr + adc[r]];
    }

    // ---- online softmax, lane-local row ----
    float mx = sv[0][0];
#pragma unroll
    for (int r = 1; r < 16; ++r) mx = fmaxf(mx, sv[0][r]);
#pragma unroll
    for (int r = 0; r < 16; ++r) mx = fmaxf(mx, sv[1][r]);
    mx = fmaxf(mx, __shfl_xor(mx, 32));

    if (!__all(mx - m_ <= 8.0f)) {       // defer-max: rescale only on growth
      const float nm  = fmaxf(m_, mx);
      const float fac = __expf(m_ - nm);
      m_ = nm;
      l_ *= fac;
#pragma unroll
      for (int r = 0; r < 16; ++r) {
        const float fr = __shfl(fac, (r & 3) + 8 * (r >> 2) + 4 * hi);
#pragma unroll
        for (int ds = 0; ds < 4; ++ds) o_[ds][r] *= fr;
      }
    }

    float sum = 0.f;
#pragma unroll
    for (int js = 0; js < 2; ++js)
#pragma unroll
      for (int r = 0; r < 16; ++r) {
        const float p = __expf(sv[js][r] - m_);
        sv[js][r] = p;
        sum += p;
      }
    sum += __shfl_xor(sum, 32);
    l_ += sum;

    // ---- pack P to bf16 word-pairs: wpk[js][wi] = (p[2wi], p[2wi+1]) ----
    unsigned int wpk[2][8];
#pragma unroll
    for (int js = 0; js < 2; ++js)
#pragma unroll
      for (int wi = 0; wi < 8; ++wi)
        wpk[js][wi] = (unsigned int)f2bf(sv[js][2 * wi]) |
                      ((unsigned int)f2bf(sv[js][2 * wi + 1]) << 16);

    // ---- O += P x V: redistribute P to A-frag via shfl_xor(32)+select ----
    const char* vb_ = (const char*)&vt[cur][0];
    __builtin_amdgcn_s_setprio(1);
#pragma unroll
    for (int kj = 0; kj < 4; ++kj) {
      const int js = kj >> 1, base = (kj & 1) * 4;
      const unsigned int u0 = wpk[js][base + 0], u1 = wpk[js][base + 1];
      const unsigned int u2 = wpk[js][base + 2], u3 = wpk[js][base + 3];
      const unsigned int t0 = __shfl_xor(u0, 32), t1 = __shfl_xor(u1, 32);
      const unsigned int t2 = __shfl_xor(u2, 32), t3 = __shfl_xor(u3, 32);
      union { unsigned int u[4]; bf16x8 v; } af;
      af.u[0] = hi ? t2 : u0;   // j = 8hi + {0,1}
      af.u[1] = hi ? t3 : u1;   // j = 8hi + {2,3}
      af.u[2] = hi ? u2 : t0;   // j = 8hi + {4,5}
      af.u[3] = hi ? u3 : t1;   // j = 8hi + {6,7}
#pragma unroll
      for (int ds = 0; ds < 4; ++ds) {
        const int d = ds * 32 + c;
        bf16x8 vf = *(const bf16x8*)(vb_ + d * 128 + ((kj * 32 + hi * 16) ^ ((d & 7) << 4)));
        o_[ds] = mfma32(af.v, vf, o_[ds]);
      }
    }
    __builtin_amdgcn_s_setprio(0);

    __syncthreads();      // all reads of cur done; next iter stages into cur
    cur ^= 1;
  }

  // ---- normalize + write attn_out[b][n][h*128+d] ----
#pragma unroll
  for (int r = 0; r < 16; ++r) {
    const int qloc = (r & 3) + 8 * (r >> 2) + 4 * hi;
    const float lr = __shfl(l_, qloc);
    const float inv = 1.f / lr;
    const size_t rowb = (size_t)b * 1024 * 2048 + (size_t)(qbase + qloc) * 2048 + h * 128;
#pragma unroll
    for (int ds = 0; ds < 4; ++ds)
      aout[rowb + ds * 32 + c] = f2bf(o_[ds][r] * inv);
  }
}

// ---------------------------------------------------------------------------
extern "C" void kernel_launch(void* const* d_in, const int* in_sizes, int n_in,
                              void* d_out, int out_size, void* d_ws, size_t ws_size,
                              hipStream_t stream)
{
  const float* x      = (const float*)d_in[0];
  const float* ln_g   = (const float*)d_in[1];
  const float* ln_b   = (const float*)d_in[2];
  const float* qkv_w  = (const float*)d_in[3];
  const float* qkv_b  = (const float*)d_in[4];
  const float* proj_w = (const float*)d_in[5];
  const float* proj_b = (const float*)d_in[6];
  const float* ab     = (const float*)d_in[7];
  float* out = (float*)d_out;
  char* ws = (char*)d_ws;

  unsigned short* xn = (unsigned short*)(ws);                             // 64 MiB; reused as attn_out
  unsigned short* wt = (unsigned short*)(ws + (size_t)64  * 1024 * 1024); // 24 MiB
  unsigned short* qb = (unsigned short*)(ws + (size_t)88  * 1024 * 1024);
  unsigned short* kb = (unsigned short*)(ws + (size_t)152 * 1024 * 1024);
  unsigned short* vb = (unsigned short*)(ws + (size_t)216 * 1024 * 1024);
  const int n_off = in_sizes[7] / 16;   // = 1024

  ln_kernel<<<16384, 256, 0, stream>>>(x, ln_g, ln_b, xn);
  wtrans<<<dim3(6144 / 32, 2048 / 32), 256, 0, stream>>>(qkv_w, wt, 2048, 6144);
  gemm_nt<0><<<dim3(24, 64), 512, 0, stream>>>(xn, wt, qkv_b, qb, kb, vb, 2048, 6144);
  wtrans<<<dim3(2048 / 32, 2048 / 32), 256, 0, stream>>>(proj_w, wt, 2048, 2048);
  attn4<<<2048, 256, 0, stream>>>(qb, kb, vb, ab, xn, n_off);
  gemm_nt<1><<<dim3(8, 64), 512, 0, stream>>>(xn, wt, proj_b, out, nullptr, nullptr, 2048, 2048);
}